// Round 1
// baseline (404.918 us; speedup 1.0000x reference)
//
#include <hip/hip_runtime.h>

#define BB 2
#define NN 384
#define CC 1024
#define HR 256      // H_REPN
#define GH 256      // G_HID
#define NHEADS 4
#define TOPK 8
#define CAP 448
#define NEG 0.2f

// ---------------- zero counts ----------------
__global__ void k_zero(int* __restrict__ counts) {
    int i = blockIdx.x * blockDim.x + threadIdx.x;
    if (i < BB * NN) counts[i] = 0;
}

// ---------------- p1 = f@Wa + b, p2t = (f@Wb)^T ----------------
__global__ __launch_bounds__(256) void k_p12(const float* __restrict__ feats,
        const float* __restrict__ fc1_w, const float* __restrict__ fc1_b,
        float* __restrict__ p1, float* __restrict__ p2t) {
    __shared__ float ft[8][CC];
    int blk = blockIdx.x;            // B*N/8 blocks
    int b   = blk / (NN / 8);
    int r0  = (blk % (NN / 8)) * 8;
    int t   = threadIdx.x;
    const float* fbase = feats + ((size_t)b * NN + r0) * CC;
    for (int idx = t; idx < 8 * CC; idx += 256) ft[idx >> 10][idx & (CC - 1)] = fbase[idx];
    __syncthreads();
    float acc1[8], acc2[8];
#pragma unroll
    for (int r = 0; r < 8; r++) { acc1[r] = 0.f; acc2[r] = 0.f; }
    for (int k = 0; k < CC; k++) {
        float wa = fc1_w[(size_t)k * HR + t];
        float wb = fc1_w[(size_t)(CC + k) * HR + t];
#pragma unroll
        for (int r = 0; r < 8; r++) {
            float f = ft[r][k];
            acc1[r] += f * wa;
            acc2[r] += f * wb;
        }
    }
    float bias = fc1_b[t];
#pragma unroll
    for (int r = 0; r < 8; r++) {
        int row = r0 + r;
        p1[((size_t)b * NN + row) * HR + t] = acc1[r] + bias;
        p2t[((size_t)b * HR + t) * NN + row] = acc2[r];
    }
}

// ---------------- rel[i,j] ----------------
__global__ __launch_bounds__(384) void k_rel(const float* __restrict__ p1,
        const float* __restrict__ p2t, const float* __restrict__ boxes,
        const float* __restrict__ fc1_w, const float* __restrict__ fc2_w,
        const float* __restrict__ fc2_b, float* __restrict__ rel) {
    __shared__ float p1s[4][HR];
    __shared__ float wg[4][HR];
    __shared__ float w2s[HR];
    __shared__ float bxi[4][4];
    int blk = blockIdx.x;            // B*(N/4) blocks
    int b   = blk / (NN / 4);
    int i0  = (blk % (NN / 4)) * 4;
    int t   = threadIdx.x;           // 0..383
    for (int idx = t; idx < 4 * HR; idx += 384)
        p1s[idx / HR][idx % HR] = p1[((size_t)b * NN + i0 + idx / HR) * HR + (idx % HR)];
    for (int idx = t; idx < 4 * HR; idx += 384)
        wg[idx / HR][idx % HR] = fc1_w[(size_t)(2 * CC + idx / HR) * HR + (idx % HR)];
    for (int idx = t; idx < HR; idx += 384) w2s[idx] = fc2_w[idx];
    if (t < 16) bxi[t >> 2][t & 3] = boxes[((size_t)b * NN + i0 + (t >> 2)) * 4 + (t & 3)];
    __syncthreads();
    int j = t;
    float bxj[4];
#pragma unroll
    for (int k = 0; k < 4; k++) bxj[k] = boxes[((size_t)b * NN + j) * 4 + k];
    float g[4][4];
#pragma unroll
    for (int r = 0; r < 4; r++)
#pragma unroll
        for (int k = 0; k < 4; k++) g[r][k] = fabsf(bxi[r][k] - bxj[k]);
    float acc[4] = {0.f, 0.f, 0.f, 0.f};
    const float* p2row = p2t + (size_t)b * HR * NN;
    for (int c = 0; c < HR; c++) {
        float p2v = p2row[(size_t)c * NN + j];
        float w0 = wg[0][c], w1 = wg[1][c], wv2 = wg[2][c], w3 = wg[3][c];
        float wc = w2s[c];
#pragma unroll
        for (int r = 0; r < 4; r++) {
            float v = p1s[r][c] + p2v + g[r][0] * w0 + g[r][1] * w1 + g[r][2] * wv2 + g[r][3] * w3;
            v = fmaxf(v, 0.f);
            acc[r] += v * wc;
        }
    }
    float b2 = fc2_b[0];
#pragma unroll
    for (int r = 0; r < 4; r++) {
        int i = i0 + r;
        float v = acc[r] + b2;
        if (j == i) v -= 1000000.0f;
        rel[((size_t)b * NN + i) * NN + j] = v;
    }
}

// ---------------- top-8 per row ----------------
__global__ __launch_bounds__(64) void k_topk(const float* __restrict__ rel, int* __restrict__ nbr) {
    int row = blockIdx.x;            // b*N+i
    int t = threadIdx.x;
    const float* r = rel + (size_t)row * NN;
    float v[6]; int id[6];
#pragma unroll
    for (int q = 0; q < 6; q++) { int j = t + q * 64; v[q] = r[j]; id[q] = j; }
    for (int k = 0; k < TOPK; k++) {
        float bv = -INFINITY; int bi = NN;
#pragma unroll
        for (int q = 0; q < 6; q++) {
            if (v[q] > bv || (v[q] == bv && id[q] < bi)) { bv = v[q]; bi = id[q]; }
        }
        for (int off = 32; off > 0; off >>= 1) {
            float ov = __shfl_down(bv, off);
            int   oi = __shfl_down(bi, off);
            if (ov > bv || (ov == bv && oi < bi)) { bv = ov; bi = oi; }
        }
        bi = __shfl(bi, 0);
        if (t == 0) nbr[(size_t)row * TOPK + k] = bi;
#pragma unroll
        for (int q = 0; q < 6; q++) if (id[q] == bi) v[q] = -INFINITY;
    }
}

// ---------------- invert edges ----------------
__global__ void k_inv(const int* __restrict__ nbr, int* __restrict__ counts, int* __restrict__ inlist) {
    int idx = blockIdx.x * blockDim.x + threadIdx.x;   // b*N+i
    if (idx >= BB * NN) return;
    int b = idx / NN; int i = idx % NN;
    int p = atomicAdd(&counts[idx], 1);
    inlist[(size_t)idx * CAP + p] = i;
#pragma unroll
    for (int k = 0; k < TOPK; k++) {
        int tg = b * NN + nbr[(size_t)idx * TOPK + k];
        int q = atomicAdd(&counts[tg], 1);
        inlist[(size_t)tg * CAP + q] = i;
    }
}

// ---------------- xw1 = [f|geom] @ gat1_w ----------------
__global__ __launch_bounds__(256) void k_xw1(const float* __restrict__ feats,
        const float* __restrict__ boxes, const float* __restrict__ w,
        float* __restrict__ xw1) {
    __shared__ float xt[8][CC + 4];
    int blk = blockIdx.x;                 // B * 48 * 4
    int b  = blk / 192;
    int rt = (blk % 192) / 4;
    int ct = blk % 4;
    int r0 = rt * 8;
    int t  = threadIdx.x;
    int col = ct * 256 + t;
    const float inv800 = 1.0f / 800.0f;
    for (int idx = t; idx < 8 * (CC + 4); idx += 256) {
        int r = idx / (CC + 4), k = idx % (CC + 4);
        int row = r0 + r;
        float v;
        if (k < CC) v = feats[((size_t)b * NN + row) * CC + k];
        else {
            const float* bx = boxes + ((size_t)b * NN + row) * 4;
            int gk = k - CC;
            v = (gk == 0) ? bx[0] * inv800
              : (gk == 1) ? bx[1] * inv800
              : (gk == 2) ? (bx[2] * inv800 - bx[0] * inv800)
                          : (bx[3] * inv800 - bx[1] * inv800);
        }
        xt[r][k] = v;
    }
    __syncthreads();
    float acc[8];
#pragma unroll
    for (int r = 0; r < 8; r++) acc[r] = 0.f;
    for (int k = 0; k < CC + 4; k++) {
        float wv = w[(size_t)k * 1024 + col];
#pragma unroll
        for (int r = 0; r < 8; r++) acc[r] += xt[r][k] * wv;
    }
#pragma unroll
    for (int r = 0; r < 8; r++)
        xw1[((size_t)b * NN + r0 + r) * 1024 + col] = acc[r];
}

// ---------------- attention dots for GAT1 ----------------
__global__ __launch_bounds__(256) void k_att1(const float* __restrict__ xw1,
        const float* __restrict__ att_src, const float* __restrict__ att_dst,
        float* __restrict__ a_s, float* __restrict__ a_d) {
    __shared__ float red[512];
    int node = blockIdx.x;
    int t = threadIdx.x;
    const float* xr = xw1 + (size_t)node * 1024;
    float ps[NHEADS], pd[NHEADS];
#pragma unroll
    for (int h = 0; h < NHEADS; h++) {
        float x = xr[h * 256 + t];
        ps[h] = x * att_src[h * 256 + t];
        pd[h] = x * att_dst[h * 256 + t];
    }
    for (int h = 0; h < NHEADS; h++) {
        red[t] = ps[h]; red[256 + t] = pd[h];
        __syncthreads();
        for (int s = 128; s > 0; s >>= 1) {
            if (t < s) { red[t] += red[t + s]; red[256 + t] += red[256 + t + s]; }
            __syncthreads();
        }
        if (t == 0) { a_s[(size_t)node * NHEADS + h] = red[0]; a_d[(size_t)node * NHEADS + h] = red[256]; }
        __syncthreads();
    }
}

// ---------------- GAT1 aggregation ----------------
__global__ __launch_bounds__(256) void k_agg1(const int* __restrict__ counts,
        const int* __restrict__ inlist, const float* __restrict__ a_s,
        const float* __restrict__ a_d, const float* __restrict__ xw1,
        const float* __restrict__ gat1_b, float* __restrict__ h1) {
    __shared__ int slist[CAP];
    __shared__ float warr[512];
    __shared__ float red[256];
    int node = blockIdx.x;
    int b = node / NN;
    int t = threadIdx.x;
    int deg = counts[node];
    for (int e = t; e < deg; e += 256) slist[e] = inlist[(size_t)node * CAP + e];
    __syncthreads();
    for (int h = 0; h < NHEADS; h++) {
        float ad = a_d[(size_t)node * NHEADS + h];
        for (int e = t; e < 512; e += 256) {
            float ev = -INFINITY;
            if (e < deg) {
                float x = a_s[((size_t)(b * NN + slist[e])) * NHEADS + h] + ad;
                ev = x >= 0.f ? x : NEG * x;
            }
            warr[e] = ev;
        }
        __syncthreads();
        red[t] = fmaxf(warr[t], warr[t + 256]);
        __syncthreads();
        for (int s = 128; s > 0; s >>= 1) { if (t < s) red[t] = fmaxf(red[t], red[t + s]); __syncthreads(); }
        float m = red[0];
        __syncthreads();
        for (int e = t; e < 512; e += 256) warr[e] = (e < deg) ? expf(warr[e] - m) : 0.f;
        __syncthreads();
        red[t] = warr[t] + warr[t + 256];
        __syncthreads();
        for (int s = 128; s > 0; s >>= 1) { if (t < s) red[t] += red[t + s]; __syncthreads(); }
        float denom = fmaxf(red[0], 1e-16f);
        __syncthreads();
        float acc = 0.f;
        for (int e = 0; e < deg; e++) {
            float wv = warr[e];
            acc += wv * xw1[((size_t)(b * NN + slist[e])) * 1024 + h * 256 + t];
        }
        float o = acc / denom + gat1_b[h * 256 + t];
        h1[(size_t)node * 1024 + h * 256 + t] = fmaxf(o, 0.f);
        __syncthreads();
    }
}

// ---------------- GAT2 projections + attention dots ----------------
__global__ __launch_bounds__(256) void k_xw2att(const float* __restrict__ h1,
        const float* __restrict__ w2, const float* __restrict__ as2,
        const float* __restrict__ ad2, float* __restrict__ xw2,
        float* __restrict__ a_s2, float* __restrict__ a_d2) {
    __shared__ float red[512];
    int node = blockIdx.x;
    int t = threadIdx.x;
    const float* hr = h1 + (size_t)node * 1024;
    float p0 = 0.f, p1v = 0.f;
    for (int c = t; c < 1024; c += 256) {
        float v = hr[c];
        p0  += v * w2[c * 2];
        p1v += v * w2[c * 2 + 1];
    }
    red[t] = p0; red[256 + t] = p1v;
    __syncthreads();
    for (int s = 128; s > 0; s >>= 1) {
        if (t < s) { red[t] += red[t + s]; red[256 + t] += red[256 + t + s]; }
        __syncthreads();
    }
    if (t == 0) {
        float x0 = red[0], x1 = red[256];
        xw2[(size_t)node * 2] = x0; xw2[(size_t)node * 2 + 1] = x1;
        a_s2[node] = x0 * as2[0] + x1 * as2[1];
        a_d2[node] = x0 * ad2[0] + x1 * ad2[1];
    }
}

// ---------------- GAT2 aggregation -> output ----------------
__global__ __launch_bounds__(256) void k_agg2(const int* __restrict__ counts,
        const int* __restrict__ inlist, const float* __restrict__ a_s2,
        const float* __restrict__ a_d2, const float* __restrict__ xw2,
        const float* __restrict__ b2, float* __restrict__ out) {
    __shared__ int slist[CAP];
    __shared__ float warr[512];
    __shared__ float red[256];
    int node = blockIdx.x;
    int b = node / NN;
    int t = threadIdx.x;
    int deg = counts[node];
    for (int e = t; e < deg; e += 256) slist[e] = inlist[(size_t)node * CAP + e];
    __syncthreads();
    float ad = a_d2[node];
    for (int e = t; e < 512; e += 256) {
        float ev = -INFINITY;
        if (e < deg) {
            float x = a_s2[b * NN + slist[e]] + ad;
            ev = x >= 0.f ? x : NEG * x;
        }
        warr[e] = ev;
    }
    __syncthreads();
    red[t] = fmaxf(warr[t], warr[t + 256]);
    __syncthreads();
    for (int s = 128; s > 0; s >>= 1) { if (t < s) red[t] = fmaxf(red[t], red[t + s]); __syncthreads(); }
    float m = red[0];
    __syncthreads();
    for (int e = t; e < 512; e += 256) warr[e] = (e < deg) ? expf(warr[e] - m) : 0.f;
    __syncthreads();
    red[t] = warr[t] + warr[t + 256];
    __syncthreads();
    for (int s = 128; s > 0; s >>= 1) { if (t < s) red[t] += red[t + s]; __syncthreads(); }
    float denom = fmaxf(red[0], 1e-16f);
    __syncthreads();
    if (t < 2) {
        float acc = 0.f;
        for (int e = 0; e < deg; e++)
            acc += warr[e] * xw2[(size_t)(b * NN + slist[e]) * 2 + t];
        out[(size_t)node * 2 + t] = acc / denom + b2[t];
    }
}

extern "C" void kernel_launch(void* const* d_in, const int* in_sizes, int n_in,
                              void* d_out, int out_size, void* d_ws, size_t ws_size,
                              hipStream_t stream) {
    const float* feats  = (const float*)d_in[0];
    const float* boxes  = (const float*)d_in[1];
    const float* fc1_w  = (const float*)d_in[2];
    const float* fc1_b  = (const float*)d_in[3];
    const float* fc2_w  = (const float*)d_in[4];
    const float* fc2_b  = (const float*)d_in[5];
    const float* gat1_w = (const float*)d_in[6];
    const float* g1as   = (const float*)d_in[7];
    const float* g1ad   = (const float*)d_in[8];
    const float* gat1_b = (const float*)d_in[9];
    const float* gat2_w = (const float*)d_in[10];
    const float* g2as   = (const float*)d_in[11];
    const float* g2ad   = (const float*)d_in[12];
    const float* gat2_b = (const float*)d_in[13];
    float* out = (float*)d_out;

    char* ws = (char*)d_ws;
    size_t off = 0;
    auto alloc = [&](size_t bytes) -> void* {
        void* p = ws + off;
        off += (bytes + 255) / 256 * 256;
        return p;
    };
    int*   counts = (int*)alloc((size_t)BB * NN * 4);
    int*   nbr    = (int*)alloc((size_t)BB * NN * TOPK * 4);
    int*   inlist = (int*)alloc((size_t)BB * NN * CAP * 4);
    float* p1     = (float*)alloc((size_t)BB * NN * HR * 4);
    float* p2t    = (float*)alloc((size_t)BB * HR * NN * 4);
    float* rel    = (float*)alloc((size_t)BB * NN * NN * 4);
    float* xw1    = (float*)alloc((size_t)BB * NN * 1024 * 4);
    float* a_s1   = (float*)alloc((size_t)BB * NN * NHEADS * 4);
    float* a_d1   = (float*)alloc((size_t)BB * NN * NHEADS * 4);
    float* h1     = (float*)alloc((size_t)BB * NN * 1024 * 4);
    float* xw2    = (float*)alloc((size_t)BB * NN * 2 * 4);
    float* as2f   = (float*)alloc((size_t)BB * NN * 4);
    float* ad2f   = (float*)alloc((size_t)BB * NN * 4);
    (void)ws_size; (void)in_sizes; (void)n_in; (void)out_size;

    k_zero<<<(BB * NN + 255) / 256, 256, 0, stream>>>(counts);
    k_p12<<<BB * NN / 8, 256, 0, stream>>>(feats, fc1_w, fc1_b, p1, p2t);
    k_rel<<<BB * (NN / 4), 384, 0, stream>>>(p1, p2t, boxes, fc1_w, fc2_w, fc2_b, rel);
    k_topk<<<BB * NN, 64, 0, stream>>>(rel, nbr);
    k_inv<<<(BB * NN + 255) / 256, 256, 0, stream>>>(nbr, counts, inlist);
    k_xw1<<<BB * 192, 256, 0, stream>>>(feats, boxes, gat1_w, xw1);
    k_att1<<<BB * NN, 256, 0, stream>>>(xw1, g1as, g1ad, a_s1, a_d1);
    k_agg1<<<BB * NN, 256, 0, stream>>>(counts, inlist, a_s1, a_d1, xw1, gat1_b, h1);
    k_xw2att<<<BB * NN, 256, 0, stream>>>(h1, gat2_w, g2as, g2ad, xw2, as2f, ad2f);
    k_agg2<<<BB * NN, 256, 0, stream>>>(counts, inlist, as2f, ad2f, xw2, gat2_b, out);
}

// Round 2
// 271.145 us; speedup vs baseline: 1.4934x; 1.4934x over previous
//
#include <hip/hip_runtime.h>

#define BB 2
#define NN 384
#define CC 1024
#define HR 256      // H_REPN
#define NHEADS 4
#define TOPK 8
#define CAP 448
#define NEG 0.2f

typedef __attribute__((ext_vector_type(8))) short bf16x8;
typedef __attribute__((ext_vector_type(4))) float f32x4;

__device__ __forceinline__ unsigned short f2bf(float v) {
    unsigned u = __float_as_uint(v);
    return (unsigned short)((u + 0x7FFFu + ((u >> 16) & 1u)) >> 16);
}

// ---------------- zero counts ----------------
__global__ void k_zero(int* __restrict__ counts) {
    int i = blockIdx.x * blockDim.x + threadIdx.x;
    if (i < BB * NN) counts[i] = 0;
}

// ---------------- prep A (bf16 swizzled [feats|geom|0], Kp=1056) ----------------
// layout: uint4 index = mt*33*64 + kc*64 + lane ; lane = q*16 + mm
// element j of that uint4 = A[m = mt*16+mm][k = kc*32 + q*8 + j]
__global__ void k_prepa(const float* __restrict__ feats, const float* __restrict__ boxes,
                        uint4* __restrict__ Asw) {
    int flat = blockIdx.x * 256 + threadIdx.x;
    if (flat >= 48 * 33 * 64) return;
    int lane = flat & 63;
    int kc = (flat >> 6) % 33;
    int mt = flat / (33 * 64);
    int m = mt * 16 + (lane & 15);
    int k0 = kc * 32 + (lane >> 4) * 8;
    unsigned short vals[8];
    const float s = 1.0f / 800.0f;
#pragma unroll
    for (int j = 0; j < 8; j++) {
        int k = k0 + j;
        float v;
        if (k < CC) v = feats[(size_t)m * CC + k];
        else if (k < CC + 4) {
            const float* bx = boxes + (size_t)m * 4;
            int gk = k - CC;
            v = (gk == 0) ? bx[0] * s : (gk == 1) ? bx[1] * s
              : (gk == 2) ? (bx[2] - bx[0]) * s : (bx[3] - bx[1]) * s;
        } else v = 0.f;
        vals[j] = f2bf(v);
    }
    uint4 pk;
    pk.x = (unsigned)vals[0] | ((unsigned)vals[1] << 16);
    pk.y = (unsigned)vals[2] | ((unsigned)vals[3] << 16);
    pk.z = (unsigned)vals[4] | ((unsigned)vals[5] << 16);
    pk.w = (unsigned)vals[6] | ((unsigned)vals[7] << 16);
    Asw[flat] = pk;
}

// ---------------- prep B (bf16 swizzled gat1_w, Kp=1056) ----------------
// uint4 index = nt*33*64 + kc*64 + lane ; lane = q*16 + nn
// element j = W[k = kc*32+q*8+j][n = nt*16+nn]  (zero for k>=1028)
__global__ void k_prepb(const float* __restrict__ w, uint4* __restrict__ Bsw) {
    int flat = blockIdx.x * 256 + threadIdx.x;
    if (flat >= 64 * 33 * 64) return;
    int lane = flat & 63;
    int kc = (flat >> 6) % 33;
    int nt = flat / (33 * 64);
    int n = nt * 16 + (lane & 15);
    int k0 = kc * 32 + (lane >> 4) * 8;
    unsigned short vals[8];
#pragma unroll
    for (int j = 0; j < 8; j++) {
        int k = k0 + j;
        float v = (k < CC + 4) ? w[(size_t)k * 1024 + n] : 0.f;
        vals[j] = f2bf(v);
    }
    uint4 pk;
    pk.x = (unsigned)vals[0] | ((unsigned)vals[1] << 16);
    pk.y = (unsigned)vals[2] | ((unsigned)vals[3] << 16);
    pk.z = (unsigned)vals[4] | ((unsigned)vals[5] << 16);
    pk.w = (unsigned)vals[6] | ((unsigned)vals[7] << 16);
    Bsw[flat] = pk;
}

// ---------------- xw1 via MFMA bf16 ----------------
__global__ __launch_bounds__(256) void k_xw1m(const uint4* __restrict__ Asw,
        const uint4* __restrict__ Bsw, float* __restrict__ xw1) {
    int t = threadIdx.x;
    int w = t >> 6;
    int lane = t & 63;
    int blk = blockIdx.x;            // mt*16 + ntgrp
    int mt = blk >> 4;
    int nt = (blk & 15) * 4 + w;
    f32x4 acc = {0.f, 0.f, 0.f, 0.f};
    const uint4* pa = Asw + (size_t)mt * 33 * 64 + lane;
    const uint4* pb = Bsw + (size_t)nt * 33 * 64 + lane;
#pragma unroll 4
    for (int kc = 0; kc < 33; kc++) {
        uint4 av = pa[kc * 64];
        uint4 bv = pb[kc * 64];
        acc = __builtin_amdgcn_mfma_f32_16x16x32_bf16(*(bf16x8*)&av, *(bf16x8*)&bv, acc, 0, 0, 0);
    }
    int col = nt * 16 + (lane & 15);
    int row0 = mt * 16 + (lane >> 4) * 4;
#pragma unroll
    for (int r = 0; r < 4; r++)
        xw1[(size_t)(row0 + r) * 1024 + col] = acc[r];
}

// ---------------- p1/p2 K-split f32 GEMM partials ----------------
__global__ __launch_bounds__(256) void k_p12s(const float* __restrict__ feats,
        const float* __restrict__ fc1_w, float* __restrict__ part) {
    __shared__ float As[256][17];
    int blk = blockIdx.x;            // ks*384 + mt*8 + nt
    int ks = blk / 384;
    int mt = (blk % 384) / 8;
    int nt = blk % 8;
    int t = threadIdx.x;
#pragma unroll
    for (int i = 0; i < 16; i++) {
        int rr = mt * 16 + i;
        As[t][i] = feats[(size_t)rr * 1024 + ks * 256 + t];
    }
    __syncthreads();
    int m = t & 15;
    int ng = t >> 4;
    const float* Bbase = (nt < 4) ? (fc1_w + nt * 64 + ng * 4)
                                  : (fc1_w + (size_t)1024 * 256 + (nt - 4) * 64 + ng * 4);
    Bbase += (size_t)ks * 256 * 256;
    float a0 = 0.f, a1 = 0.f, a2 = 0.f, a3 = 0.f;
#pragma unroll 4
    for (int k = 0; k < 256; k++) {
        float av = As[k][m];
        float4 bv = *(const float4*)(Bbase + (size_t)k * 256);
        a0 += av * bv.x; a1 += av * bv.y; a2 += av * bv.z; a3 += av * bv.w;
    }
    size_t o = ((size_t)ks * 768 + mt * 16 + m) * 512 + nt * 64 + ng * 4;
    part[o + 0] = a0; part[o + 1] = a1; part[o + 2] = a2; part[o + 3] = a3;
}

// ---------------- reduce partials -> p1 (+bias), p2t (transposed) ----------------
__global__ void k_p12r(const float* __restrict__ part, const float* __restrict__ fc1_b,
                       float* __restrict__ p1, float* __restrict__ p2t) {
    int idx = blockIdx.x * 256 + threadIdx.x;
    if (idx >= 768 * 512) return;
    int rr = idx >> 9;
    int n = idx & 511;
    float s = part[idx] + part[idx + 768 * 512] + part[idx + 2 * 768 * 512] + part[idx + 3 * 768 * 512];
    if (n < 256) p1[(size_t)rr * 256 + n] = s + fc1_b[n];
    else {
        int b = rr / NN, r = rr % NN;
        p2t[((size_t)b * 256 + (n - 256)) * NN + r] = s;
    }
}

// ---------------- rel[i,j] (2 rows / block) ----------------
__global__ __launch_bounds__(384) void k_rel(const float* __restrict__ p1,
        const float* __restrict__ p2t, const float* __restrict__ boxes,
        const float* __restrict__ fc1_w, const float* __restrict__ fc2_w,
        const float* __restrict__ fc2_b, float* __restrict__ rel) {
    __shared__ float p1s[2][HR];
    __shared__ float wg[4][HR];
    __shared__ float w2s[HR];
    __shared__ float bxi[2][4];
    int blk = blockIdx.x;            // B*(N/2) blocks
    int b   = blk / (NN / 2);
    int i0  = (blk % (NN / 2)) * 2;
    int t   = threadIdx.x;           // 0..383
    for (int idx = t; idx < 2 * HR; idx += 384)
        p1s[idx >> 8][idx & 255] = p1[((size_t)b * NN + i0 + (idx >> 8)) * HR + (idx & 255)];
    for (int idx = t; idx < 4 * HR; idx += 384)
        wg[idx >> 8][idx & 255] = fc1_w[(size_t)(2 * CC + (idx >> 8)) * HR + (idx & 255)];
    for (int idx = t; idx < HR; idx += 384) w2s[idx] = fc2_w[idx];
    if (t < 8) bxi[t >> 2][t & 3] = boxes[((size_t)b * NN + i0 + (t >> 2)) * 4 + (t & 3)];
    __syncthreads();
    int j = t;
    float bxj[4];
#pragma unroll
    for (int k = 0; k < 4; k++) bxj[k] = boxes[((size_t)b * NN + j) * 4 + k];
    float g[2][4];
#pragma unroll
    for (int r = 0; r < 2; r++)
#pragma unroll
        for (int k = 0; k < 4; k++) g[r][k] = fabsf(bxi[r][k] - bxj[k]);
    float acc[2] = {0.f, 0.f};
    const float* p2row = p2t + (size_t)b * HR * NN;
#pragma unroll 4
    for (int c = 0; c < HR; c++) {
        float p2v = p2row[(size_t)c * NN + j];
        float w0 = wg[0][c], w1 = wg[1][c], wv2 = wg[2][c], w3 = wg[3][c];
        float wc = w2s[c];
#pragma unroll
        for (int r = 0; r < 2; r++) {
            float v = p1s[r][c] + p2v + g[r][0] * w0 + g[r][1] * w1 + g[r][2] * wv2 + g[r][3] * w3;
            v = fmaxf(v, 0.f);
            acc[r] += v * wc;
        }
    }
    float b2 = fc2_b[0];
#pragma unroll
    for (int r = 0; r < 2; r++) {
        int i = i0 + r;
        float v = acc[r] + b2;
        if (j == i) v -= 1000000.0f;
        rel[((size_t)b * NN + i) * NN + j] = v;
    }
}

// ---------------- top-8 per row ----------------
__global__ __launch_bounds__(64) void k_topk(const float* __restrict__ rel, int* __restrict__ nbr) {
    int row = blockIdx.x;            // b*N+i
    int t = threadIdx.x;
    const float* r = rel + (size_t)row * NN;
    float v[6]; int id[6];
#pragma unroll
    for (int q = 0; q < 6; q++) { int j = t + q * 64; v[q] = r[j]; id[q] = j; }
    for (int k = 0; k < TOPK; k++) {
        float bv = -INFINITY; int bi = NN;
#pragma unroll
        for (int q = 0; q < 6; q++) {
            if (v[q] > bv || (v[q] == bv && id[q] < bi)) { bv = v[q]; bi = id[q]; }
        }
        for (int off = 32; off > 0; off >>= 1) {
            float ov = __shfl_down(bv, off);
            int   oi = __shfl_down(bi, off);
            if (ov > bv || (ov == bv && oi < bi)) { bv = ov; bi = oi; }
        }
        bi = __shfl(bi, 0);
        if (t == 0) nbr[(size_t)row * TOPK + k] = bi;
#pragma unroll
        for (int q = 0; q < 6; q++) if (id[q] == bi) v[q] = -INFINITY;
    }
}

// ---------------- invert edges ----------------
__global__ void k_inv(const int* __restrict__ nbr, int* __restrict__ counts, int* __restrict__ inlist) {
    int idx = blockIdx.x * blockDim.x + threadIdx.x;   // b*N+i
    if (idx >= BB * NN) return;
    int b = idx / NN; int i = idx % NN;
    int p = atomicAdd(&counts[idx], 1);
    inlist[(size_t)idx * CAP + p] = i;
#pragma unroll
    for (int k = 0; k < TOPK; k++) {
        int tg = b * NN + nbr[(size_t)idx * TOPK + k];
        int q = atomicAdd(&counts[tg], 1);
        inlist[(size_t)tg * CAP + q] = i;
    }
}

// ---------------- attention dots for GAT1 ----------------
__global__ __launch_bounds__(256) void k_att1(const float* __restrict__ xw1,
        const float* __restrict__ att_src, const float* __restrict__ att_dst,
        float* __restrict__ a_s, float* __restrict__ a_d) {
    __shared__ float red[512];
    int node = blockIdx.x;
    int t = threadIdx.x;
    const float* xr = xw1 + (size_t)node * 1024;
    float ps[NHEADS], pd[NHEADS];
#pragma unroll
    for (int h = 0; h < NHEADS; h++) {
        float x = xr[h * 256 + t];
        ps[h] = x * att_src[h * 256 + t];
        pd[h] = x * att_dst[h * 256 + t];
    }
    for (int h = 0; h < NHEADS; h++) {
        red[t] = ps[h]; red[256 + t] = pd[h];
        __syncthreads();
        for (int s = 128; s > 0; s >>= 1) {
            if (t < s) { red[t] += red[t + s]; red[256 + t] += red[256 + t + s]; }
            __syncthreads();
        }
        if (t == 0) { a_s[(size_t)node * NHEADS + h] = red[0]; a_d[(size_t)node * NHEADS + h] = red[256]; }
        __syncthreads();
    }
}

// ---------------- GAT1 aggregation ----------------
__global__ __launch_bounds__(256) void k_agg1(const int* __restrict__ counts,
        const int* __restrict__ inlist, const float* __restrict__ a_s,
        const float* __restrict__ a_d, const float* __restrict__ xw1,
        const float* __restrict__ gat1_b, float* __restrict__ h1) {
    __shared__ int slist[CAP];
    __shared__ float warr[512];
    __shared__ float red[256];
    int node = blockIdx.x;
    int b = node / NN;
    int t = threadIdx.x;
    int deg = counts[node];
    for (int e = t; e < deg; e += 256) slist[e] = inlist[(size_t)node * CAP + e];
    __syncthreads();
    for (int h = 0; h < NHEADS; h++) {
        float ad = a_d[(size_t)node * NHEADS + h];
        for (int e = t; e < 512; e += 256) {
            float ev = -INFINITY;
            if (e < deg) {
                float x = a_s[((size_t)(b * NN + slist[e])) * NHEADS + h] + ad;
                ev = x >= 0.f ? x : NEG * x;
            }
            warr[e] = ev;
        }
        __syncthreads();
        red[t] = fmaxf(warr[t], warr[t + 256]);
        __syncthreads();
        for (int s = 128; s > 0; s >>= 1) { if (t < s) red[t] = fmaxf(red[t], red[t + s]); __syncthreads(); }
        float m = red[0];
        __syncthreads();
        for (int e = t; e < 512; e += 256) warr[e] = (e < deg) ? expf(warr[e] - m) : 0.f;
        __syncthreads();
        red[t] = warr[t] + warr[t + 256];
        __syncthreads();
        for (int s = 128; s > 0; s >>= 1) { if (t < s) red[t] += red[t + s]; __syncthreads(); }
        float denom = fmaxf(red[0], 1e-16f);
        __syncthreads();
        float acc = 0.f;
        for (int e = 0; e < deg; e++) {
            float wv = warr[e];
            acc += wv * xw1[((size_t)(b * NN + slist[e])) * 1024 + h * 256 + t];
        }
        float o = acc / denom + gat1_b[h * 256 + t];
        h1[(size_t)node * 1024 + h * 256 + t] = fmaxf(o, 0.f);
        __syncthreads();
    }
}

// ---------------- GAT2 projections + attention dots ----------------
__global__ __launch_bounds__(256) void k_xw2att(const float* __restrict__ h1,
        const float* __restrict__ w2, const float* __restrict__ as2,
        const float* __restrict__ ad2, float* __restrict__ xw2,
        float* __restrict__ a_s2, float* __restrict__ a_d2) {
    __shared__ float red[512];
    int node = blockIdx.x;
    int t = threadIdx.x;
    const float* hr = h1 + (size_t)node * 1024;
    float p0 = 0.f, p1v = 0.f;
    for (int c = t; c < 1024; c += 256) {
        float v = hr[c];
        p0  += v * w2[c * 2];
        p1v += v * w2[c * 2 + 1];
    }
    red[t] = p0; red[256 + t] = p1v;
    __syncthreads();
    for (int s = 128; s > 0; s >>= 1) {
        if (t < s) { red[t] += red[t + s]; red[256 + t] += red[256 + t + s]; }
        __syncthreads();
    }
    if (t == 0) {
        float x0 = red[0], x1 = red[256];
        xw2[(size_t)node * 2] = x0; xw2[(size_t)node * 2 + 1] = x1;
        a_s2[node] = x0 * as2[0] + x1 * as2[1];
        a_d2[node] = x0 * ad2[0] + x1 * ad2[1];
    }
}

// ---------------- GAT2 aggregation -> output ----------------
__global__ __launch_bounds__(256) void k_agg2(const int* __restrict__ counts,
        const int* __restrict__ inlist, const float* __restrict__ a_s2,
        const float* __restrict__ a_d2, const float* __restrict__ xw2,
        const float* __restrict__ b2, float* __restrict__ out) {
    __shared__ int slist[CAP];
    __shared__ float warr[512];
    __shared__ float red[256];
    int node = blockIdx.x;
    int b = node / NN;
    int t = threadIdx.x;
    int deg = counts[node];
    for (int e = t; e < deg; e += 256) slist[e] = inlist[(size_t)node * CAP + e];
    __syncthreads();
    float ad = a_d2[node];
    for (int e = t; e < 512; e += 256) {
        float ev = -INFINITY;
        if (e < deg) {
            float x = a_s2[b * NN + slist[e]] + ad;
            ev = x >= 0.f ? x : NEG * x;
        }
        warr[e] = ev;
    }
    __syncthreads();
    red[t] = fmaxf(warr[t], warr[t + 256]);
    __syncthreads();
    for (int s = 128; s > 0; s >>= 1) { if (t < s) red[t] = fmaxf(red[t], red[t + s]); __syncthreads(); }
    float m = red[0];
    __syncthreads();
    for (int e = t; e < 512; e += 256) warr[e] = (e < deg) ? expf(warr[e] - m) : 0.f;
    __syncthreads();
    red[t] = warr[t] + warr[t + 256];
    __syncthreads();
    for (int s = 128; s > 0; s >>= 1) { if (t < s) red[t] += red[t + s]; __syncthreads(); }
    float denom = fmaxf(red[0], 1e-16f);
    __syncthreads();
    if (t < 2) {
        float acc = 0.f;
        for (int e = 0; e < deg; e++)
            acc += warr[e] * xw2[(size_t)(b * NN + slist[e]) * 2 + t];
        out[(size_t)node * 2 + t] = acc / denom + b2[t];
    }
}

extern "C" void kernel_launch(void* const* d_in, const int* in_sizes, int n_in,
                              void* d_out, int out_size, void* d_ws, size_t ws_size,
                              hipStream_t stream) {
    const float* feats  = (const float*)d_in[0];
    const float* boxes  = (const float*)d_in[1];
    const float* fc1_w  = (const float*)d_in[2];
    const float* fc1_b  = (const float*)d_in[3];
    const float* fc2_w  = (const float*)d_in[4];
    const float* fc2_b  = (const float*)d_in[5];
    const float* gat1_w = (const float*)d_in[6];
    const float* g1as   = (const float*)d_in[7];
    const float* g1ad   = (const float*)d_in[8];
    const float* gat1_b = (const float*)d_in[9];
    const float* gat2_w = (const float*)d_in[10];
    const float* g2as   = (const float*)d_in[11];
    const float* g2ad   = (const float*)d_in[12];
    const float* gat2_b = (const float*)d_in[13];
    float* out = (float*)d_out;

    char* ws = (char*)d_ws;
    size_t off = 0;
    auto alloc = [&](size_t bytes) -> void* {
        void* p = ws + off;
        off += (bytes + 255) / 256 * 256;
        return p;
    };
    int*   counts = (int*)alloc((size_t)BB * NN * 4);
    int*   nbr    = (int*)alloc((size_t)BB * NN * TOPK * 4);
    int*   inlist = (int*)alloc((size_t)BB * NN * CAP * 4);
    float* p1     = (float*)alloc((size_t)BB * NN * HR * 4);
    float* p2t    = (float*)alloc((size_t)BB * HR * NN * 4);
    float* rel    = (float*)alloc((size_t)BB * NN * NN * 4);
    float* xw1    = (float*)alloc((size_t)BB * NN * 1024 * 4);
    float* a_s1   = (float*)alloc((size_t)BB * NN * NHEADS * 4);
    float* a_d1   = (float*)alloc((size_t)BB * NN * NHEADS * 4);
    float* h1     = (float*)alloc((size_t)BB * NN * 1024 * 4);
    float* xw2    = (float*)alloc((size_t)BB * NN * 2 * 4);
    float* as2f   = (float*)alloc((size_t)BB * NN * 4);
    float* ad2f   = (float*)alloc((size_t)BB * NN * 4);
    float* part   = (float*)alloc((size_t)4 * 768 * 512 * 4);
    uint4* Asw    = (uint4*)alloc((size_t)48 * 33 * 64 * 16);
    uint4* Bsw    = (uint4*)alloc((size_t)64 * 33 * 64 * 16);
    (void)ws_size; (void)in_sizes; (void)n_in; (void)out_size;

    k_zero<<<(BB * NN + 255) / 256, 256, 0, stream>>>(counts);
    k_prepa<<<(48 * 33 * 64 + 255) / 256, 256, 0, stream>>>(feats, boxes, Asw);
    k_prepb<<<(64 * 33 * 64 + 255) / 256, 256, 0, stream>>>(gat1_w, Bsw);
    k_p12s<<<4 * 384, 256, 0, stream>>>(feats, fc1_w, part);
    k_p12r<<<(768 * 512 + 255) / 256, 256, 0, stream>>>(part, fc1_b, p1, p2t);
    k_rel<<<BB * (NN / 2), 384, 0, stream>>>(p1, p2t, boxes, fc1_w, fc2_w, fc2_b, rel);
    k_topk<<<BB * NN, 64, 0, stream>>>(rel, nbr);
    k_inv<<<(BB * NN + 255) / 256, 256, 0, stream>>>(nbr, counts, inlist);
    k_xw1m<<<48 * 16, 256, 0, stream>>>(Asw, Bsw, xw1);
    k_att1<<<BB * NN, 256, 0, stream>>>(xw1, g1as, g1ad, a_s1, a_d1);
    k_agg1<<<BB * NN, 256, 0, stream>>>(counts, inlist, a_s1, a_d1, xw1, gat1_b, h1);
    k_xw2att<<<BB * NN, 256, 0, stream>>>(h1, gat2_w, g2as, g2ad, xw2, as2f, ad2f);
    k_agg2<<<BB * NN, 256, 0, stream>>>(counts, inlist, as2f, ad2f, xw2, gat2_b, out);
}

// Round 3
// 235.273 us; speedup vs baseline: 1.7211x; 1.1525x over previous
//
#include <hip/hip_runtime.h>

#define BB 2
#define NN 384
#define CC 1024
#define HR 256      // H_REPN
#define NHEADS 4
#define TOPK 8
#define CAP 448
#define NEG 0.2f

typedef __attribute__((ext_vector_type(8))) short bf16x8;
typedef __attribute__((ext_vector_type(4))) float f32x4;

__device__ __forceinline__ unsigned short f2bf(float v) {
    unsigned u = __float_as_uint(v);
    return (unsigned short)((u + 0x7FFFu + ((u >> 16) & 1u)) >> 16);
}
__device__ __forceinline__ float bf2f(unsigned short h) {
    return __uint_as_float((unsigned)h << 16);
}

// ---------------- zero counts ----------------
__global__ void k_zero(int* __restrict__ counts) {
    int i = blockIdx.x * blockDim.x + threadIdx.x;
    if (i < BB * NN) counts[i] = 0;
}

// ---------------- prep A (bf16 swizzled [feats|geom|0], Kp=1056) for xw1 ----------------
__global__ void k_prepa(const float* __restrict__ feats, const float* __restrict__ boxes,
                        uint4* __restrict__ Asw) {
    int flat = blockIdx.x * 256 + threadIdx.x;
    if (flat >= 48 * 33 * 64) return;
    int lane = flat & 63;
    int kc = (flat >> 6) % 33;
    int mt = flat / (33 * 64);
    int m = mt * 16 + (lane & 15);
    int k0 = kc * 32 + (lane >> 4) * 8;
    unsigned short vals[8];
    const float s = 1.0f / 800.0f;
#pragma unroll
    for (int j = 0; j < 8; j++) {
        int k = k0 + j;
        float v;
        if (k < CC) v = feats[(size_t)m * CC + k];
        else if (k < CC + 4) {
            const float* bx = boxes + (size_t)m * 4;
            int gk = k - CC;
            v = (gk == 0) ? bx[0] * s : (gk == 1) ? bx[1] * s
              : (gk == 2) ? (bx[2] - bx[0]) * s : (bx[3] - bx[1]) * s;
        } else v = 0.f;
        vals[j] = f2bf(v);
    }
    uint4 pk;
    pk.x = (unsigned)vals[0] | ((unsigned)vals[1] << 16);
    pk.y = (unsigned)vals[2] | ((unsigned)vals[3] << 16);
    pk.z = (unsigned)vals[4] | ((unsigned)vals[5] << 16);
    pk.w = (unsigned)vals[6] | ((unsigned)vals[7] << 16);
    Asw[flat] = pk;
}

// ---------------- prep B (bf16 swizzled gat1_w, Kp=1056) for xw1 ----------------
__global__ void k_prepb(const float* __restrict__ w, uint4* __restrict__ Bsw) {
    int flat = blockIdx.x * 256 + threadIdx.x;
    if (flat >= 64 * 33 * 64) return;
    int lane = flat & 63;
    int kc = (flat >> 6) % 33;
    int nt = flat / (33 * 64);
    int n = nt * 16 + (lane & 15);
    int k0 = kc * 32 + (lane >> 4) * 8;
    unsigned short vals[8];
#pragma unroll
    for (int j = 0; j < 8; j++) {
        int k = k0 + j;
        float v = (k < CC + 4) ? w[(size_t)k * 1024 + n] : 0.f;
        vals[j] = f2bf(v);
    }
    uint4 pk;
    pk.x = (unsigned)vals[0] | ((unsigned)vals[1] << 16);
    pk.y = (unsigned)vals[2] | ((unsigned)vals[3] << 16);
    pk.z = (unsigned)vals[4] | ((unsigned)vals[5] << 16);
    pk.w = (unsigned)vals[6] | ((unsigned)vals[7] << 16);
    Bsw[flat] = pk;
}

// ---------------- xw1 via MFMA bf16 ----------------
__global__ __launch_bounds__(256) void k_xw1m(const uint4* __restrict__ Asw,
        const uint4* __restrict__ Bsw, float* __restrict__ xw1) {
    int t = threadIdx.x;
    int w = t >> 6;
    int lane = t & 63;
    int blk = blockIdx.x;            // mt*16 + ntgrp
    int mt = blk >> 4;
    int nt = (blk & 15) * 4 + w;
    f32x4 acc = {0.f, 0.f, 0.f, 0.f};
    const uint4* pa = Asw + (size_t)mt * 33 * 64 + lane;
    const uint4* pb = Bsw + (size_t)nt * 33 * 64 + lane;
#pragma unroll 4
    for (int kc = 0; kc < 33; kc++) {
        uint4 av = pa[kc * 64];
        uint4 bv = pb[kc * 64];
        acc = __builtin_amdgcn_mfma_f32_16x16x32_bf16(*(bf16x8*)&av, *(bf16x8*)&bv, acc, 0, 0, 0);
    }
    int col = nt * 16 + (lane & 15);
    int row0 = mt * 16 + (lane >> 4) * 4;
#pragma unroll
    for (int r = 0; r < 4; r++)
        xw1[(size_t)(row0 + r) * 1024 + col] = acc[r];
}

// ---------------- prep A hi/lo (feats, split-bf16, K=1024) for p12 ----------------
__global__ void k_prepa2(const float* __restrict__ feats,
                         uint4* __restrict__ Ah, uint4* __restrict__ Al) {
    int flat = blockIdx.x * 256 + threadIdx.x;
    if (flat >= 48 * 32 * 64) return;
    int lane = flat & 63;
    int kc = (flat >> 6) % 32;
    int mt = flat / (32 * 64);
    int m = mt * 16 + (lane & 15);
    int k0 = kc * 32 + (lane >> 4) * 8;
    unsigned short vh[8], vl[8];
    const float* src = feats + (size_t)m * CC + k0;
#pragma unroll
    for (int j = 0; j < 8; j++) {
        float v = src[j];
        unsigned short h = f2bf(v);
        vh[j] = h;
        vl[j] = f2bf(v - bf2f(h));
    }
    uint4 ph, pl;
    ph.x = (unsigned)vh[0] | ((unsigned)vh[1] << 16);
    ph.y = (unsigned)vh[2] | ((unsigned)vh[3] << 16);
    ph.z = (unsigned)vh[4] | ((unsigned)vh[5] << 16);
    ph.w = (unsigned)vh[6] | ((unsigned)vh[7] << 16);
    pl.x = (unsigned)vl[0] | ((unsigned)vl[1] << 16);
    pl.y = (unsigned)vl[2] | ((unsigned)vl[3] << 16);
    pl.z = (unsigned)vl[4] | ((unsigned)vl[5] << 16);
    pl.w = (unsigned)vl[6] | ((unsigned)vl[7] << 16);
    Ah[flat] = ph; Al[flat] = pl;
}

// ---------------- prep B hi/lo ([Wa|Wb] as 1024x512, split-bf16) for p12 ----------------
__global__ void k_prepb2(const float* __restrict__ fc1_w,
                         uint4* __restrict__ Bh, uint4* __restrict__ Bl) {
    int flat = blockIdx.x * 256 + threadIdx.x;
    if (flat >= 32 * 32 * 64) return;
    int lane = flat & 63;
    int kc = (flat >> 6) % 32;
    int nt = flat / (32 * 64);
    int n = nt * 16 + (lane & 15);
    int k0 = kc * 32 + (lane >> 4) * 8;
    unsigned short vh[8], vl[8];
#pragma unroll
    for (int j = 0; j < 8; j++) {
        int k = k0 + j;
        float v = (n < 256) ? fc1_w[(size_t)k * 256 + n]
                            : fc1_w[(size_t)(CC + k) * 256 + (n - 256)];
        unsigned short h = f2bf(v);
        vh[j] = h;
        vl[j] = f2bf(v - bf2f(h));
    }
    uint4 ph, pl;
    ph.x = (unsigned)vh[0] | ((unsigned)vh[1] << 16);
    ph.y = (unsigned)vh[2] | ((unsigned)vh[3] << 16);
    ph.z = (unsigned)vh[4] | ((unsigned)vh[5] << 16);
    ph.w = (unsigned)vh[6] | ((unsigned)vh[7] << 16);
    pl.x = (unsigned)vl[0] | ((unsigned)vl[1] << 16);
    pl.y = (unsigned)vl[2] | ((unsigned)vl[3] << 16);
    pl.z = (unsigned)vl[4] | ((unsigned)vl[5] << 16);
    pl.w = (unsigned)vl[6] | ((unsigned)vl[7] << 16);
    Bh[flat] = ph; Bl[flat] = pl;
}

// ---------------- p1/p2 via split-bf16 MFMA (3 products) ----------------
__global__ __launch_bounds__(256) void k_p12m(const uint4* __restrict__ Ah,
        const uint4* __restrict__ Al, const uint4* __restrict__ Bh,
        const uint4* __restrict__ Bl, const float* __restrict__ fc1_b,
        float* __restrict__ p1, float* __restrict__ p2t) {
    int t = threadIdx.x;
    int w = t >> 6;
    int lane = t & 63;
    int blk = blockIdx.x;            // mt*8 + ntg
    int mt = blk >> 3;
    int nt = (blk & 7) * 4 + w;
    f32x4 acc = {0.f, 0.f, 0.f, 0.f};
    const uint4* pah = Ah + (size_t)mt * 32 * 64 + lane;
    const uint4* pal = Al + (size_t)mt * 32 * 64 + lane;
    const uint4* pbh = Bh + (size_t)nt * 32 * 64 + lane;
    const uint4* pbl = Bl + (size_t)nt * 32 * 64 + lane;
#pragma unroll 4
    for (int kc = 0; kc < 32; kc++) {
        uint4 ah = pah[kc * 64];
        uint4 al = pal[kc * 64];
        uint4 bh = pbh[kc * 64];
        uint4 bl = pbl[kc * 64];
        acc = __builtin_amdgcn_mfma_f32_16x16x32_bf16(*(bf16x8*)&ah, *(bf16x8*)&bh, acc, 0, 0, 0);
        acc = __builtin_amdgcn_mfma_f32_16x16x32_bf16(*(bf16x8*)&ah, *(bf16x8*)&bl, acc, 0, 0, 0);
        acc = __builtin_amdgcn_mfma_f32_16x16x32_bf16(*(bf16x8*)&al, *(bf16x8*)&bh, acc, 0, 0, 0);
    }
    int col = nt * 16 + (lane & 15);
    int row0 = mt * 16 + (lane >> 4) * 4;
    if (col < 256) {
        float bias = fc1_b[col];
#pragma unroll
        for (int r = 0; r < 4; r++)
            p1[(size_t)(row0 + r) * 256 + col] = acc[r] + bias;
    } else {
#pragma unroll
        for (int r = 0; r < 4; r++) {
            int rr = row0 + r;
            int b = rr / NN, rloc = rr % NN;
            p2t[((size_t)b * 256 + (col - 256)) * NN + rloc] = acc[r];
        }
    }
}

// ---------------- rel[i,j] (2 rows / block) ----------------
__global__ __launch_bounds__(384) void k_rel(const float* __restrict__ p1,
        const float* __restrict__ p2t, const float* __restrict__ boxes,
        const float* __restrict__ fc1_w, const float* __restrict__ fc2_w,
        const float* __restrict__ fc2_b, float* __restrict__ rel) {
    __shared__ float p1s[2][HR];
    __shared__ float wg[4][HR];
    __shared__ float w2s[HR];
    __shared__ float bxi[2][4];
    int blk = blockIdx.x;            // B*(N/2) blocks
    int b   = blk / (NN / 2);
    int i0  = (blk % (NN / 2)) * 2;
    int t   = threadIdx.x;           // 0..383
    for (int idx = t; idx < 2 * HR; idx += 384)
        p1s[idx >> 8][idx & 255] = p1[((size_t)b * NN + i0 + (idx >> 8)) * HR + (idx & 255)];
    for (int idx = t; idx < 4 * HR; idx += 384)
        wg[idx >> 8][idx & 255] = fc1_w[(size_t)(2 * CC + (idx >> 8)) * HR + (idx & 255)];
    for (int idx = t; idx < HR; idx += 384) w2s[idx] = fc2_w[idx];
    if (t < 8) bxi[t >> 2][t & 3] = boxes[((size_t)b * NN + i0 + (t >> 2)) * 4 + (t & 3)];
    __syncthreads();
    int j = t;
    float bxj[4];
#pragma unroll
    for (int k = 0; k < 4; k++) bxj[k] = boxes[((size_t)b * NN + j) * 4 + k];
    float g[2][4];
#pragma unroll
    for (int r = 0; r < 2; r++)
#pragma unroll
        for (int k = 0; k < 4; k++) g[r][k] = fabsf(bxi[r][k] - bxj[k]);
    float acc[2] = {0.f, 0.f};
    const float* p2row = p2t + (size_t)b * HR * NN;
#pragma unroll 4
    for (int c = 0; c < HR; c++) {
        float p2v = p2row[(size_t)c * NN + j];
        float w0 = wg[0][c], w1 = wg[1][c], wv2 = wg[2][c], w3 = wg[3][c];
        float wc = w2s[c];
#pragma unroll
        for (int r = 0; r < 2; r++) {
            float v = p1s[r][c] + p2v + g[r][0] * w0 + g[r][1] * w1 + g[r][2] * wv2 + g[r][3] * w3;
            v = fmaxf(v, 0.f);
            acc[r] += v * wc;
        }
    }
    float b2 = fc2_b[0];
#pragma unroll
    for (int r = 0; r < 2; r++) {
        int i = i0 + r;
        float v = acc[r] + b2;
        if (j == i) v -= 1000000.0f;
        rel[((size_t)b * NN + i) * NN + j] = v;
    }
}

// ---------------- top-8 per row ----------------
__global__ __launch_bounds__(64) void k_topk(const float* __restrict__ rel, int* __restrict__ nbr) {
    int row = blockIdx.x;            // b*N+i
    int t = threadIdx.x;
    const float* r = rel + (size_t)row * NN;
    float v[6]; int id[6];
#pragma unroll
    for (int q = 0; q < 6; q++) { int j = t + q * 64; v[q] = r[j]; id[q] = j; }
    for (int k = 0; k < TOPK; k++) {
        float bv = -INFINITY; int bi = NN;
#pragma unroll
        for (int q = 0; q < 6; q++) {
            if (v[q] > bv || (v[q] == bv && id[q] < bi)) { bv = v[q]; bi = id[q]; }
        }
        for (int off = 32; off > 0; off >>= 1) {
            float ov = __shfl_down(bv, off);
            int   oi = __shfl_down(bi, off);
            if (ov > bv || (ov == bv && oi < bi)) { bv = ov; bi = oi; }
        }
        bi = __shfl(bi, 0);
        if (t == 0) nbr[(size_t)row * TOPK + k] = bi;
#pragma unroll
        for (int q = 0; q < 6; q++) if (id[q] == bi) v[q] = -INFINITY;
    }
}

// ---------------- invert edges ----------------
__global__ void k_inv(const int* __restrict__ nbr, int* __restrict__ counts, int* __restrict__ inlist) {
    int idx = blockIdx.x * blockDim.x + threadIdx.x;   // b*N+i
    if (idx >= BB * NN) return;
    int b = idx / NN; int i = idx % NN;
    int p = atomicAdd(&counts[idx], 1);
    inlist[(size_t)idx * CAP + p] = i;
#pragma unroll
    for (int k = 0; k < TOPK; k++) {
        int tg = b * NN + nbr[(size_t)idx * TOPK + k];
        int q = atomicAdd(&counts[tg], 1);
        inlist[(size_t)tg * CAP + q] = i;
    }
}

// ---------------- attention dots for GAT1 ----------------
__global__ __launch_bounds__(256) void k_att1(const float* __restrict__ xw1,
        const float* __restrict__ att_src, const float* __restrict__ att_dst,
        float* __restrict__ a_s, float* __restrict__ a_d) {
    __shared__ float red[512];
    int node = blockIdx.x;
    int t = threadIdx.x;
    const float* xr = xw1 + (size_t)node * 1024;
    float ps[NHEADS], pd[NHEADS];
#pragma unroll
    for (int h = 0; h < NHEADS; h++) {
        float x = xr[h * 256 + t];
        ps[h] = x * att_src[h * 256 + t];
        pd[h] = x * att_dst[h * 256 + t];
    }
    for (int h = 0; h < NHEADS; h++) {
        red[t] = ps[h]; red[256 + t] = pd[h];
        __syncthreads();
        for (int s = 128; s > 0; s >>= 1) {
            if (t < s) { red[t] += red[t + s]; red[256 + t] += red[256 + t + s]; }
            __syncthreads();
        }
        if (t == 0) { a_s[(size_t)node * NHEADS + h] = red[0]; a_d[(size_t)node * NHEADS + h] = red[256]; }
        __syncthreads();
    }
}

// ---------------- GAT1 aggregation ----------------
__global__ __launch_bounds__(256) void k_agg1(const int* __restrict__ counts,
        const int* __restrict__ inlist, const float* __restrict__ a_s,
        const float* __restrict__ a_d, const float* __restrict__ xw1,
        const float* __restrict__ gat1_b, float* __restrict__ h1) {
    __shared__ int slist[CAP];
    __shared__ float warr[512];
    __shared__ float red[256];
    int node = blockIdx.x;
    int b = node / NN;
    int t = threadIdx.x;
    int deg = counts[node];
    for (int e = t; e < deg; e += 256) slist[e] = inlist[(size_t)node * CAP + e];
    __syncthreads();
    for (int h = 0; h < NHEADS; h++) {
        float ad = a_d[(size_t)node * NHEADS + h];
        for (int e = t; e < 512; e += 256) {
            float ev = -INFINITY;
            if (e < deg) {
                float x = a_s[((size_t)(b * NN + slist[e])) * NHEADS + h] + ad;
                ev = x >= 0.f ? x : NEG * x;
            }
            warr[e] = ev;
        }
        __syncthreads();
        red[t] = fmaxf(warr[t], warr[t + 256]);
        __syncthreads();
        for (int s = 128; s > 0; s >>= 1) { if (t < s) red[t] = fmaxf(red[t], red[t + s]); __syncthreads(); }
        float m = red[0];
        __syncthreads();
        for (int e = t; e < 512; e += 256) warr[e] = (e < deg) ? expf(warr[e] - m) : 0.f;
        __syncthreads();
        red[t] = warr[t] + warr[t + 256];
        __syncthreads();
        for (int s = 128; s > 0; s >>= 1) { if (t < s) red[t] += red[t + s]; __syncthreads(); }
        float denom = fmaxf(red[0], 1e-16f);
        __syncthreads();
        float acc = 0.f;
        for (int e = 0; e < deg; e++) {
            float wv = warr[e];
            acc += wv * xw1[((size_t)(b * NN + slist[e])) * 1024 + h * 256 + t];
        }
        float o = acc / denom + gat1_b[h * 256 + t];
        h1[(size_t)node * 1024 + h * 256 + t] = fmaxf(o, 0.f);
        __syncthreads();
    }
}

// ---------------- GAT2 projections + attention dots ----------------
__global__ __launch_bounds__(256) void k_xw2att(const float* __restrict__ h1,
        const float* __restrict__ w2, const float* __restrict__ as2,
        const float* __restrict__ ad2, float* __restrict__ xw2,
        float* __restrict__ a_s2, float* __restrict__ a_d2) {
    __shared__ float red[512];
    int node = blockIdx.x;
    int t = threadIdx.x;
    const float* hr = h1 + (size_t)node * 1024;
    float p0 = 0.f, p1v = 0.f;
    for (int c = t; c < 1024; c += 256) {
        float v = hr[c];
        p0  += v * w2[c * 2];
        p1v += v * w2[c * 2 + 1];
    }
    red[t] = p0; red[256 + t] = p1v;
    __syncthreads();
    for (int s = 128; s > 0; s >>= 1) {
        if (t < s) { red[t] += red[t + s]; red[256 + t] += red[256 + t + s]; }
        __syncthreads();
    }
    if (t == 0) {
        float x0 = red[0], x1 = red[256];
        xw2[(size_t)node * 2] = x0; xw2[(size_t)node * 2 + 1] = x1;
        a_s2[node] = x0 * as2[0] + x1 * as2[1];
        a_d2[node] = x0 * ad2[0] + x1 * ad2[1];
    }
}

// ---------------- GAT2 aggregation -> output ----------------
__global__ __launch_bounds__(256) void k_agg2(const int* __restrict__ counts,
        const int* __restrict__ inlist, const float* __restrict__ a_s2,
        const float* __restrict__ a_d2, const float* __restrict__ xw2,
        const float* __restrict__ b2, float* __restrict__ out) {
    __shared__ int slist[CAP];
    __shared__ float warr[512];
    __shared__ float red[256];
    int node = blockIdx.x;
    int b = node / NN;
    int t = threadIdx.x;
    int deg = counts[node];
    for (int e = t; e < deg; e += 256) slist[e] = inlist[(size_t)node * CAP + e];
    __syncthreads();
    float ad = a_d2[node];
    for (int e = t; e < 512; e += 256) {
        float ev = -INFINITY;
        if (e < deg) {
            float x = a_s2[b * NN + slist[e]] + ad;
            ev = x >= 0.f ? x : NEG * x;
        }
        warr[e] = ev;
    }
    __syncthreads();
    red[t] = fmaxf(warr[t], warr[t + 256]);
    __syncthreads();
    for (int s = 128; s > 0; s >>= 1) { if (t < s) red[t] = fmaxf(red[t], red[t + s]); __syncthreads(); }
    float m = red[0];
    __syncthreads();
    for (int e = t; e < 512; e += 256) warr[e] = (e < deg) ? expf(warr[e] - m) : 0.f;
    __syncthreads();
    red[t] = warr[t] + warr[t + 256];
    __syncthreads();
    for (int s = 128; s > 0; s >>= 1) { if (t < s) red[t] += red[t + s]; __syncthreads(); }
    float denom = fmaxf(red[0], 1e-16f);
    __syncthreads();
    if (t < 2) {
        float acc = 0.f;
        for (int e = 0; e < deg; e++)
            acc += warr[e] * xw2[(size_t)(b * NN + slist[e]) * 2 + t];
        out[(size_t)node * 2 + t] = acc / denom + b2[t];
    }
}

extern "C" void kernel_launch(void* const* d_in, const int* in_sizes, int n_in,
                              void* d_out, int out_size, void* d_ws, size_t ws_size,
                              hipStream_t stream) {
    const float* feats  = (const float*)d_in[0];
    const float* boxes  = (const float*)d_in[1];
    const float* fc1_w  = (const float*)d_in[2];
    const float* fc1_b  = (const float*)d_in[3];
    const float* fc2_w  = (const float*)d_in[4];
    const float* fc2_b  = (const float*)d_in[5];
    const float* gat1_w = (const float*)d_in[6];
    const float* g1as   = (const float*)d_in[7];
    const float* g1ad   = (const float*)d_in[8];
    const float* gat1_b = (const float*)d_in[9];
    const float* gat2_w = (const float*)d_in[10];
    const float* g2as   = (const float*)d_in[11];
    const float* g2ad   = (const float*)d_in[12];
    const float* gat2_b = (const float*)d_in[13];
    float* out = (float*)d_out;

    char* ws = (char*)d_ws;
    size_t off = 0;
    auto alloc = [&](size_t bytes) -> void* {
        void* p = ws + off;
        off += (bytes + 255) / 256 * 256;
        return p;
    };
    int*   counts = (int*)alloc((size_t)BB * NN * 4);
    int*   nbr    = (int*)alloc((size_t)BB * NN * TOPK * 4);
    int*   inlist = (int*)alloc((size_t)BB * NN * CAP * 4);
    float* p1     = (float*)alloc((size_t)BB * NN * HR * 4);
    float* p2t    = (float*)alloc((size_t)BB * HR * NN * 4);
    float* rel    = (float*)alloc((size_t)BB * NN * NN * 4);
    float* xw1    = (float*)alloc((size_t)BB * NN * 1024 * 4);
    float* a_s1   = (float*)alloc((size_t)BB * NN * NHEADS * 4);
    float* a_d1   = (float*)alloc((size_t)BB * NN * NHEADS * 4);
    float* h1     = (float*)alloc((size_t)BB * NN * 1024 * 4);
    float* xw2    = (float*)alloc((size_t)BB * NN * 2 * 4);
    float* as2f   = (float*)alloc((size_t)BB * NN * 4);
    float* ad2f   = (float*)alloc((size_t)BB * NN * 4);
    uint4* Asw    = (uint4*)alloc((size_t)48 * 33 * 64 * 16);
    uint4* Bsw    = (uint4*)alloc((size_t)64 * 33 * 64 * 16);
    uint4* Ah     = (uint4*)alloc((size_t)48 * 32 * 64 * 16);
    uint4* Al     = (uint4*)alloc((size_t)48 * 32 * 64 * 16);
    uint4* Bh     = (uint4*)alloc((size_t)32 * 32 * 64 * 16);
    uint4* Bl     = (uint4*)alloc((size_t)32 * 32 * 64 * 16);
    (void)ws_size; (void)in_sizes; (void)n_in; (void)out_size;

    k_zero<<<(BB * NN + 255) / 256, 256, 0, stream>>>(counts);
    k_prepa<<<(48 * 33 * 64 + 255) / 256, 256, 0, stream>>>(feats, boxes, Asw);
    k_prepb<<<(64 * 33 * 64 + 255) / 256, 256, 0, stream>>>(gat1_w, Bsw);
    k_prepa2<<<(48 * 32 * 64 + 255) / 256, 256, 0, stream>>>(feats, Ah, Al);
    k_prepb2<<<(32 * 32 * 64 + 255) / 256, 256, 0, stream>>>(fc1_w, Bh, Bl);
    k_p12m<<<48 * 8, 256, 0, stream>>>(Ah, Al, Bh, Bl, fc1_b, p1, p2t);
    k_rel<<<BB * (NN / 2), 384, 0, stream>>>(p1, p2t, boxes, fc1_w, fc2_w, fc2_b, rel);
    k_topk<<<BB * NN, 64, 0, stream>>>(rel, nbr);
    k_inv<<<(BB * NN + 255) / 256, 256, 0, stream>>>(nbr, counts, inlist);
    k_xw1m<<<48 * 16, 256, 0, stream>>>(Asw, Bsw, xw1);
    k_att1<<<BB * NN, 256, 0, stream>>>(xw1, g1as, g1ad, a_s1, a_d1);
    k_agg1<<<BB * NN, 256, 0, stream>>>(counts, inlist, a_s1, a_d1, xw1, gat1_b, h1);
    k_xw2att<<<BB * NN, 256, 0, stream>>>(h1, gat2_w, g2as, g2ad, xw2, as2f, ad2f);
    k_agg2<<<BB * NN, 256, 0, stream>>>(counts, inlist, as2f, ad2f, xw2, gat2_b, out);
}

// Round 4
// 195.351 us; speedup vs baseline: 2.0728x; 1.2044x over previous
//
#include <hip/hip_runtime.h>

#define BB 2
#define NN 384
#define CC 1024
#define HR 256      // H_REPN
#define NHEADS 4
#define TOPK 8
#define CAP 448
#define NEG 0.2f

typedef __attribute__((ext_vector_type(8))) short bf16x8;
typedef __attribute__((ext_vector_type(4))) float f32x4;

__device__ __forceinline__ unsigned short f2bf(float v) {
    unsigned u = __float_as_uint(v);
    return (unsigned short)((u + 0x7FFFu + ((u >> 16) & 1u)) >> 16);
}
__device__ __forceinline__ float bf2f(unsigned short h) {
    return __uint_as_float((unsigned)h << 16);
}

// ---------------- prep A (bf16 swizzled [feats|geom|0], Kp=1056) for xw1; also zeros counts ----------------
__global__ void k_prepa(const float* __restrict__ feats, const float* __restrict__ boxes,
                        uint4* __restrict__ Asw, int* __restrict__ counts) {
    int flat = blockIdx.x * 256 + threadIdx.x;
    if (flat < BB * NN) counts[flat] = 0;
    if (flat >= 48 * 33 * 64) return;
    int lane = flat & 63;
    int kc = (flat >> 6) % 33;
    int mt = flat / (33 * 64);
    int m = mt * 16 + (lane & 15);
    int k0 = kc * 32 + (lane >> 4) * 8;
    unsigned short vals[8];
    const float s = 1.0f / 800.0f;
#pragma unroll
    for (int j = 0; j < 8; j++) {
        int k = k0 + j;
        float v;
        if (k < CC) v = feats[(size_t)m * CC + k];
        else if (k < CC + 4) {
            const float* bx = boxes + (size_t)m * 4;
            int gk = k - CC;
            v = (gk == 0) ? bx[0] * s : (gk == 1) ? bx[1] * s
              : (gk == 2) ? (bx[2] - bx[0]) * s : (bx[3] - bx[1]) * s;
        } else v = 0.f;
        vals[j] = f2bf(v);
    }
    uint4 pk;
    pk.x = (unsigned)vals[0] | ((unsigned)vals[1] << 16);
    pk.y = (unsigned)vals[2] | ((unsigned)vals[3] << 16);
    pk.z = (unsigned)vals[4] | ((unsigned)vals[5] << 16);
    pk.w = (unsigned)vals[6] | ((unsigned)vals[7] << 16);
    Asw[flat] = pk;
}

// ---------------- prep B (bf16 swizzled gat1_w, Kp=1056) for xw1 ----------------
__global__ void k_prepb(const float* __restrict__ w, uint4* __restrict__ Bsw) {
    int flat = blockIdx.x * 256 + threadIdx.x;
    if (flat >= 64 * 33 * 64) return;
    int lane = flat & 63;
    int kc = (flat >> 6) % 33;
    int nt = flat / (33 * 64);
    int n = nt * 16 + (lane & 15);
    int k0 = kc * 32 + (lane >> 4) * 8;
    unsigned short vals[8];
#pragma unroll
    for (int j = 0; j < 8; j++) {
        int k = k0 + j;
        float v = (k < CC + 4) ? w[(size_t)k * 1024 + n] : 0.f;
        vals[j] = f2bf(v);
    }
    uint4 pk;
    pk.x = (unsigned)vals[0] | ((unsigned)vals[1] << 16);
    pk.y = (unsigned)vals[2] | ((unsigned)vals[3] << 16);
    pk.z = (unsigned)vals[4] | ((unsigned)vals[5] << 16);
    pk.w = (unsigned)vals[6] | ((unsigned)vals[7] << 16);
    Bsw[flat] = pk;
}

// ---------------- xw1 via MFMA bf16 ----------------
__global__ __launch_bounds__(256) void k_xw1m(const uint4* __restrict__ Asw,
        const uint4* __restrict__ Bsw, float* __restrict__ xw1) {
    int t = threadIdx.x;
    int w = t >> 6;
    int lane = t & 63;
    int blk = blockIdx.x;            // mt*16 + ntgrp
    int mt = blk >> 4;
    int nt = (blk & 15) * 4 + w;
    f32x4 acc = {0.f, 0.f, 0.f, 0.f};
    const uint4* pa = Asw + (size_t)mt * 33 * 64 + lane;
    const uint4* pb = Bsw + (size_t)nt * 33 * 64 + lane;
#pragma unroll 4
    for (int kc = 0; kc < 33; kc++) {
        uint4 av = pa[kc * 64];
        uint4 bv = pb[kc * 64];
        acc = __builtin_amdgcn_mfma_f32_16x16x32_bf16(*(bf16x8*)&av, *(bf16x8*)&bv, acc, 0, 0, 0);
    }
    int col = nt * 16 + (lane & 15);
    int row0 = mt * 16 + (lane >> 4) * 4;
#pragma unroll
    for (int r = 0; r < 4; r++)
        xw1[(size_t)(row0 + r) * 1024 + col] = acc[r];
}

// ---------------- prep A hi/lo (feats, split-bf16, K=1024) for p12 ----------------
__global__ void k_prepa2(const float* __restrict__ feats,
                         uint4* __restrict__ Ah, uint4* __restrict__ Al) {
    int flat = blockIdx.x * 256 + threadIdx.x;
    if (flat >= 48 * 32 * 64) return;
    int lane = flat & 63;
    int kc = (flat >> 6) % 32;
    int mt = flat / (32 * 64);
    int m = mt * 16 + (lane & 15);
    int k0 = kc * 32 + (lane >> 4) * 8;
    unsigned short vh[8], vl[8];
    const float* src = feats + (size_t)m * CC + k0;
#pragma unroll
    for (int j = 0; j < 8; j++) {
        float v = src[j];
        unsigned short h = f2bf(v);
        vh[j] = h;
        vl[j] = f2bf(v - bf2f(h));
    }
    uint4 ph, pl;
    ph.x = (unsigned)vh[0] | ((unsigned)vh[1] << 16);
    ph.y = (unsigned)vh[2] | ((unsigned)vh[3] << 16);
    ph.z = (unsigned)vh[4] | ((unsigned)vh[5] << 16);
    ph.w = (unsigned)vh[6] | ((unsigned)vh[7] << 16);
    pl.x = (unsigned)vl[0] | ((unsigned)vl[1] << 16);
    pl.y = (unsigned)vl[2] | ((unsigned)vl[3] << 16);
    pl.z = (unsigned)vl[4] | ((unsigned)vl[5] << 16);
    pl.w = (unsigned)vl[6] | ((unsigned)vl[7] << 16);
    Ah[flat] = ph; Al[flat] = pl;
}

// ---------------- prep B hi/lo ([Wa|Wb] as 1024x512, split-bf16) for p12 ----------------
__global__ void k_prepb2(const float* __restrict__ fc1_w,
                         uint4* __restrict__ Bh, uint4* __restrict__ Bl) {
    int flat = blockIdx.x * 256 + threadIdx.x;
    if (flat >= 32 * 32 * 64) return;
    int lane = flat & 63;
    int kc = (flat >> 6) % 32;
    int nt = flat / (32 * 64);
    int n = nt * 16 + (lane & 15);
    int k0 = kc * 32 + (lane >> 4) * 8;
    unsigned short vh[8], vl[8];
#pragma unroll
    for (int j = 0; j < 8; j++) {
        int k = k0 + j;
        float v = (n < 256) ? fc1_w[(size_t)k * 256 + n]
                            : fc1_w[(size_t)(CC + k) * 256 + (n - 256)];
        unsigned short h = f2bf(v);
        vh[j] = h;
        vl[j] = f2bf(v - bf2f(h));
    }
    uint4 ph, pl;
    ph.x = (unsigned)vh[0] | ((unsigned)vh[1] << 16);
    ph.y = (unsigned)vh[2] | ((unsigned)vh[3] << 16);
    ph.z = (unsigned)vh[4] | ((unsigned)vh[5] << 16);
    ph.w = (unsigned)vh[6] | ((unsigned)vh[7] << 16);
    pl.x = (unsigned)vl[0] | ((unsigned)vl[1] << 16);
    pl.y = (unsigned)vl[2] | ((unsigned)vl[3] << 16);
    pl.z = (unsigned)vl[4] | ((unsigned)vl[5] << 16);
    pl.w = (unsigned)vl[6] | ((unsigned)vl[7] << 16);
    Bh[flat] = ph; Bl[flat] = pl;
}

// ---------------- p1/p2 via split-bf16 MFMA (3 products) ----------------
__global__ __launch_bounds__(256) void k_p12m(const uint4* __restrict__ Ah,
        const uint4* __restrict__ Al, const uint4* __restrict__ Bh,
        const uint4* __restrict__ Bl, const float* __restrict__ fc1_b,
        float* __restrict__ p1, float* __restrict__ p2t) {
    int t = threadIdx.x;
    int w = t >> 6;
    int lane = t & 63;
    int blk = blockIdx.x;            // mt*8 + ntg
    int mt = blk >> 3;
    int nt = (blk & 7) * 4 + w;
    f32x4 acc = {0.f, 0.f, 0.f, 0.f};
    const uint4* pah = Ah + (size_t)mt * 32 * 64 + lane;
    const uint4* pal = Al + (size_t)mt * 32 * 64 + lane;
    const uint4* pbh = Bh + (size_t)nt * 32 * 64 + lane;
    const uint4* pbl = Bl + (size_t)nt * 32 * 64 + lane;
#pragma unroll 4
    for (int kc = 0; kc < 32; kc++) {
        uint4 ah = pah[kc * 64];
        uint4 al = pal[kc * 64];
        uint4 bh = pbh[kc * 64];
        uint4 bl = pbl[kc * 64];
        acc = __builtin_amdgcn_mfma_f32_16x16x32_bf16(*(bf16x8*)&ah, *(bf16x8*)&bh, acc, 0, 0, 0);
        acc = __builtin_amdgcn_mfma_f32_16x16x32_bf16(*(bf16x8*)&ah, *(bf16x8*)&bl, acc, 0, 0, 0);
        acc = __builtin_amdgcn_mfma_f32_16x16x32_bf16(*(bf16x8*)&al, *(bf16x8*)&bh, acc, 0, 0, 0);
    }
    int col = nt * 16 + (lane & 15);
    int row0 = mt * 16 + (lane >> 4) * 4;
    if (col < 256) {
        float bias = fc1_b[col];
#pragma unroll
        for (int r = 0; r < 4; r++)
            p1[(size_t)(row0 + r) * 256 + col] = acc[r] + bias;
    } else {
#pragma unroll
        for (int r = 0; r < 4; r++) {
            int rr = row0 + r;
            int b = rr / NN, rloc = rr % NN;
            p2t[((size_t)b * 256 + (col - 256)) * NN + rloc] = acc[r];
        }
    }
}

// ---------------- rel[i,j] (2 rows / block) ----------------
__global__ __launch_bounds__(384) void k_rel(const float* __restrict__ p1,
        const float* __restrict__ p2t, const float* __restrict__ boxes,
        const float* __restrict__ fc1_w, const float* __restrict__ fc2_w,
        const float* __restrict__ fc2_b, float* __restrict__ rel) {
    __shared__ float p1s[2][HR];
    __shared__ float wg[4][HR];
    __shared__ float w2s[HR];
    __shared__ float bxi[2][4];
    int blk = blockIdx.x;            // B*(N/2) blocks
    int b   = blk / (NN / 2);
    int i0  = (blk % (NN / 2)) * 2;
    int t   = threadIdx.x;           // 0..383
    for (int idx = t; idx < 2 * HR; idx += 384)
        p1s[idx >> 8][idx & 255] = p1[((size_t)b * NN + i0 + (idx >> 8)) * HR + (idx & 255)];
    for (int idx = t; idx < 4 * HR; idx += 384)
        wg[idx >> 8][idx & 255] = fc1_w[(size_t)(2 * CC + (idx >> 8)) * HR + (idx & 255)];
    for (int idx = t; idx < HR; idx += 384) w2s[idx] = fc2_w[idx];
    if (t < 8) bxi[t >> 2][t & 3] = boxes[((size_t)b * NN + i0 + (t >> 2)) * 4 + (t & 3)];
    __syncthreads();
    int j = t;
    float bxj[4];
#pragma unroll
    for (int k = 0; k < 4; k++) bxj[k] = boxes[((size_t)b * NN + j) * 4 + k];
    float g[2][4];
#pragma unroll
    for (int r = 0; r < 2; r++)
#pragma unroll
        for (int k = 0; k < 4; k++) g[r][k] = fabsf(bxi[r][k] - bxj[k]);
    float acc[2] = {0.f, 0.f};
    const float* p2row = p2t + (size_t)b * HR * NN;
#pragma unroll 4
    for (int c = 0; c < HR; c++) {
        float p2v = p2row[(size_t)c * NN + j];
        float w0 = wg[0][c], w1 = wg[1][c], wv2 = wg[2][c], w3 = wg[3][c];
        float wc = w2s[c];
#pragma unroll
        for (int r = 0; r < 2; r++) {
            float v = p1s[r][c] + p2v + g[r][0] * w0 + g[r][1] * w1 + g[r][2] * wv2 + g[r][3] * w3;
            v = fmaxf(v, 0.f);
            acc[r] += v * wc;
        }
    }
    float b2 = fc2_b[0];
#pragma unroll
    for (int r = 0; r < 2; r++) {
        int i = i0 + r;
        float v = acc[r] + b2;
        if (j == i) v -= 1000000.0f;
        rel[((size_t)b * NN + i) * NN + j] = v;
    }
}

// ---------------- top-8 per row ----------------
__global__ __launch_bounds__(64) void k_topk(const float* __restrict__ rel, int* __restrict__ nbr) {
    int row = blockIdx.x;            // b*N+i
    int t = threadIdx.x;
    const float* r = rel + (size_t)row * NN;
    float v[6]; int id[6];
#pragma unroll
    for (int q = 0; q < 6; q++) { int j = t + q * 64; v[q] = r[j]; id[q] = j; }
    for (int k = 0; k < TOPK; k++) {
        float bv = -INFINITY; int bi = NN;
#pragma unroll
        for (int q = 0; q < 6; q++) {
            if (v[q] > bv || (v[q] == bv && id[q] < bi)) { bv = v[q]; bi = id[q]; }
        }
        for (int off = 32; off > 0; off >>= 1) {
            float ov = __shfl_down(bv, off);
            int   oi = __shfl_down(bi, off);
            if (ov > bv || (ov == bv && oi < bi)) { bv = ov; bi = oi; }
        }
        bi = __shfl(bi, 0);
        if (t == 0) nbr[(size_t)row * TOPK + k] = bi;
#pragma unroll
        for (int q = 0; q < 6; q++) if (id[q] == bi) v[q] = -INFINITY;
    }
}

// ---------------- invert edges ----------------
__global__ void k_inv(const int* __restrict__ nbr, int* __restrict__ counts, int* __restrict__ inlist) {
    int idx = blockIdx.x * blockDim.x + threadIdx.x;   // b*N+i
    if (idx >= BB * NN) return;
    int b = idx / NN; int i = idx % NN;
    int p = atomicAdd(&counts[idx], 1);
    inlist[(size_t)idx * CAP + p] = i;
#pragma unroll
    for (int k = 0; k < TOPK; k++) {
        int tg = b * NN + nbr[(size_t)idx * TOPK + k];
        int q = atomicAdd(&counts[tg], 1);
        inlist[(size_t)tg * CAP + q] = i;
    }
}

// ---------------- attention dots for GAT1 (wave per head) ----------------
__global__ __launch_bounds__(256) void k_att1(const float* __restrict__ xw1,
        const float* __restrict__ att_src, const float* __restrict__ att_dst,
        float* __restrict__ a_s, float* __restrict__ a_d) {
    int node = blockIdx.x;
    int w = threadIdx.x >> 6;
    int lane = threadIdx.x & 63;
    const float4* xr = (const float4*)(xw1 + (size_t)node * 1024 + w * 256);
    const float4* sr = (const float4*)(att_src + w * 256);
    const float4* dr = (const float4*)(att_dst + w * 256);
    float4 x = xr[lane];
    float4 s = sr[lane];
    float4 d = dr[lane];
    float ps = x.x * s.x + x.y * s.y + x.z * s.z + x.w * s.w;
    float pd = x.x * d.x + x.y * d.y + x.z * d.z + x.w * d.w;
#pragma unroll
    for (int off = 32; off > 0; off >>= 1) {
        ps += __shfl_xor(ps, off);
        pd += __shfl_xor(pd, off);
    }
    if (lane == 0) {
        a_s[(size_t)node * NHEADS + w] = ps;
        a_d[(size_t)node * NHEADS + w] = pd;
    }
}

// ---------------- GAT1 aggregation: one block per (node, head) ----------------
__global__ __launch_bounds__(256) void k_agg1h(const int* __restrict__ counts,
        const int* __restrict__ inlist, const float* __restrict__ a_s,
        const float* __restrict__ a_d, const float* __restrict__ xw1,
        const float* __restrict__ gat1_b, float* __restrict__ h1) {
    __shared__ int slist[CAP];
    __shared__ float walpha[CAP];
    int blk = blockIdx.x;            // node*4 + h
    int node = blk >> 2;
    int h = blk & 3;
    int b = node / NN;
    int t = threadIdx.x;
    int deg = counts[node];
    for (int e = t; e < deg; e += 256) slist[e] = inlist[(size_t)node * CAP + e];
    __syncthreads();
    if (t < 64) {
        float ad = a_d[(size_t)node * NHEADS + h];
        float vals[7];
        int cnt = 0;
        float vmax = -INFINITY;
        for (int e = t; e < deg; e += 64) {
            float x = a_s[(size_t)(b * NN + slist[e]) * NHEADS + h] + ad;
            x = x >= 0.f ? x : NEG * x;
            vals[cnt++] = x;
            vmax = fmaxf(vmax, x);
        }
#pragma unroll
        for (int off = 32; off > 0; off >>= 1)
            vmax = fmaxf(vmax, __shfl_xor(vmax, off));
        float sum = 0.f;
        for (int i = 0; i < cnt; i++) {
            vals[i] = expf(vals[i] - vmax);
            sum += vals[i];
        }
#pragma unroll
        for (int off = 32; off > 0; off >>= 1)
            sum += __shfl_xor(sum, off);
        float inv = 1.f / fmaxf(sum, 1e-16f);
        cnt = 0;
        for (int e = t; e < deg; e += 64) walpha[e] = vals[cnt++] * inv;
    }
    __syncthreads();
    float acc = 0.f;
    for (int e = 0; e < deg; e++)
        acc += walpha[e] * xw1[(size_t)(b * NN + slist[e]) * 1024 + h * 256 + t];
    float o = acc + gat1_b[h * 256 + t];
    h1[(size_t)node * 1024 + h * 256 + t] = fmaxf(o, 0.f);
}

// ---------------- GAT2 projections + attention dots (one wave per node) ----------------
__global__ __launch_bounds__(64) void k_xw2att(const float* __restrict__ h1,
        const float* __restrict__ w2, const float* __restrict__ as2,
        const float* __restrict__ ad2, float* __restrict__ xw2,
        float* __restrict__ a_s2, float* __restrict__ a_d2) {
    int node = blockIdx.x;
    int lane = threadIdx.x;
    const float4* hr = (const float4*)(h1 + (size_t)node * 1024);
    float p0 = 0.f, p1v = 0.f;
#pragma unroll
    for (int q = 0; q < 4; q++) {
        float4 v = hr[lane + q * 64];
        int c = (lane + q * 64) * 4;
        float4 wa = *(const float4*)(w2 + c * 2);
        float4 wb = *(const float4*)(w2 + c * 2 + 4);
        p0  += v.x * wa.x + v.y * wa.z + v.z * wb.x + v.w * wb.z;
        p1v += v.x * wa.y + v.y * wa.w + v.z * wb.y + v.w * wb.w;
    }
#pragma unroll
    for (int off = 32; off > 0; off >>= 1) {
        p0 += __shfl_xor(p0, off);
        p1v += __shfl_xor(p1v, off);
    }
    if (lane == 0) {
        xw2[(size_t)node * 2] = p0;
        xw2[(size_t)node * 2 + 1] = p1v;
        a_s2[node] = p0 * as2[0] + p1v * as2[1];
        a_d2[node] = p0 * ad2[0] + p1v * ad2[1];
    }
}

// ---------------- GAT2 aggregation -> output (one wave per node) ----------------
__global__ __launch_bounds__(64) void k_agg2(const int* __restrict__ counts,
        const int* __restrict__ inlist, const float* __restrict__ a_s2,
        const float* __restrict__ a_d2, const float* __restrict__ xw2,
        const float* __restrict__ b2, float* __restrict__ out) {
    int node = blockIdx.x;
    int b = node / NN;
    int lane = threadIdx.x;
    int deg = counts[node];
    float ad = a_d2[node];
    float vals[7]; int srcs[7];
    int cnt = 0;
    float vmax = -INFINITY;
    for (int e = lane; e < deg; e += 64) {
        int s = b * NN + inlist[(size_t)node * CAP + e];
        float x = a_s2[s] + ad;
        x = x >= 0.f ? x : NEG * x;
        srcs[cnt] = s; vals[cnt] = x; cnt++;
        vmax = fmaxf(vmax, x);
    }
#pragma unroll
    for (int off = 32; off > 0; off >>= 1)
        vmax = fmaxf(vmax, __shfl_xor(vmax, off));
    float sum = 0.f;
    for (int i = 0; i < cnt; i++) {
        vals[i] = expf(vals[i] - vmax);
        sum += vals[i];
    }
#pragma unroll
    for (int off = 32; off > 0; off >>= 1)
        sum += __shfl_xor(sum, off);
    float inv = 1.f / fmaxf(sum, 1e-16f);
    float a0 = 0.f, a1 = 0.f;
    for (int i = 0; i < cnt; i++) {
        a0 += vals[i] * xw2[(size_t)srcs[i] * 2];
        a1 += vals[i] * xw2[(size_t)srcs[i] * 2 + 1];
    }
#pragma unroll
    for (int off = 32; off > 0; off >>= 1) {
        a0 += __shfl_xor(a0, off);
        a1 += __shfl_xor(a1, off);
    }
    if (lane == 0) {
        out[(size_t)node * 2]     = a0 * inv + b2[0];
        out[(size_t)node * 2 + 1] = a1 * inv + b2[1];
    }
}

extern "C" void kernel_launch(void* const* d_in, const int* in_sizes, int n_in,
                              void* d_out, int out_size, void* d_ws, size_t ws_size,
                              hipStream_t stream) {
    const float* feats  = (const float*)d_in[0];
    const float* boxes  = (const float*)d_in[1];
    const float* fc1_w  = (const float*)d_in[2];
    const float* fc1_b  = (const float*)d_in[3];
    const float* fc2_w  = (const float*)d_in[4];
    const float* fc2_b  = (const float*)d_in[5];
    const float* gat1_w = (const float*)d_in[6];
    const float* g1as   = (const float*)d_in[7];
    const float* g1ad   = (const float*)d_in[8];
    const float* gat1_b = (const float*)d_in[9];
    const float* gat2_w = (const float*)d_in[10];
    const float* g2as   = (const float*)d_in[11];
    const float* g2ad   = (const float*)d_in[12];
    const float* gat2_b = (const float*)d_in[13];
    float* out = (float*)d_out;

    char* ws = (char*)d_ws;
    size_t off = 0;
    auto alloc = [&](size_t bytes) -> void* {
        void* p = ws + off;
        off += (bytes + 255) / 256 * 256;
        return p;
    };
    int*   counts = (int*)alloc((size_t)BB * NN * 4);
    int*   nbr    = (int*)alloc((size_t)BB * NN * TOPK * 4);
    int*   inlist = (int*)alloc((size_t)BB * NN * CAP * 4);
    float* p1     = (float*)alloc((size_t)BB * NN * HR * 4);
    float* p2t    = (float*)alloc((size_t)BB * HR * NN * 4);
    float* rel    = (float*)alloc((size_t)BB * NN * NN * 4);
    float* xw1    = (float*)alloc((size_t)BB * NN * 1024 * 4);
    float* a_s1   = (float*)alloc((size_t)BB * NN * NHEADS * 4);
    float* a_d1   = (float*)alloc((size_t)BB * NN * NHEADS * 4);
    float* h1     = (float*)alloc((size_t)BB * NN * 1024 * 4);
    float* xw2    = (float*)alloc((size_t)BB * NN * 2 * 4);
    float* as2f   = (float*)alloc((size_t)BB * NN * 4);
    float* ad2f   = (float*)alloc((size_t)BB * NN * 4);
    uint4* Asw    = (uint4*)alloc((size_t)48 * 33 * 64 * 16);
    uint4* Bsw    = (uint4*)alloc((size_t)64 * 33 * 64 * 16);
    uint4* Ah     = (uint4*)alloc((size_t)48 * 32 * 64 * 16);
    uint4* Al     = (uint4*)alloc((size_t)48 * 32 * 64 * 16);
    uint4* Bh     = (uint4*)alloc((size_t)32 * 32 * 64 * 16);
    uint4* Bl     = (uint4*)alloc((size_t)32 * 32 * 64 * 16);
    (void)ws_size; (void)in_sizes; (void)n_in; (void)out_size;

    k_prepa<<<(48 * 33 * 64 + 255) / 256, 256, 0, stream>>>(feats, boxes, Asw, counts);
    k_prepb<<<(64 * 33 * 64 + 255) / 256, 256, 0, stream>>>(gat1_w, Bsw);
    k_prepa2<<<(48 * 32 * 64 + 255) / 256, 256, 0, stream>>>(feats, Ah, Al);
    k_prepb2<<<(32 * 32 * 64 + 255) / 256, 256, 0, stream>>>(fc1_w, Bh, Bl);
    k_p12m<<<48 * 8, 256, 0, stream>>>(Ah, Al, Bh, Bl, fc1_b, p1, p2t);
    k_rel<<<BB * (NN / 2), 384, 0, stream>>>(p1, p2t, boxes, fc1_w, fc2_w, fc2_b, rel);
    k_topk<<<BB * NN, 64, 0, stream>>>(rel, nbr);
    k_inv<<<(BB * NN + 255) / 256, 256, 0, stream>>>(nbr, counts, inlist);
    k_xw1m<<<48 * 16, 256, 0, stream>>>(Asw, Bsw, xw1);
    k_att1<<<BB * NN, 256, 0, stream>>>(xw1, g1as, g1ad, a_s1, a_d1);
    k_agg1h<<<BB * NN * NHEADS, 256, 0, stream>>>(counts, inlist, a_s1, a_d1, xw1, gat1_b, h1);
    k_xw2att<<<BB * NN, 64, 0, stream>>>(h1, gat2_w, g2as, g2ad, xw2, as2f, ad2f);
    k_agg2<<<BB * NN, 64, 0, stream>>>(counts, inlist, as2f, ad2f, xw2, gat2_b, out);
}

// Round 5
// 167.158 us; speedup vs baseline: 2.4224x; 1.1687x over previous
//
#include <hip/hip_runtime.h>

#define BB 2
#define NN 384
#define CC 1024
#define HR 256      // H_REPN
#define NHEADS 4
#define TOPK 8
#define CAP 448
#define NEG 0.2f

typedef __attribute__((ext_vector_type(8))) short bf16x8;
typedef __attribute__((ext_vector_type(4))) float f32x4;

__device__ __forceinline__ unsigned short f2bf(float v) {
    unsigned u = __float_as_uint(v);
    return (unsigned short)((u + 0x7FFFu + ((u >> 16) & 1u)) >> 16);
}
__device__ __forceinline__ float bf2f(unsigned short h) {
    return __uint_as_float((unsigned)h << 16);
}

// ---------------- merged prep: Asw, Bsw, Ah/Al, Bh/Bl, wgp, zero counts ----------------
// block ranges: [0,396) prepa | [396,924) prepb | [924,1308) prepa2 | [1308,1564) prepb2 | 1564 wgp
__global__ __launch_bounds__(256) void k_prep(const float* __restrict__ feats,
        const float* __restrict__ boxes, const float* __restrict__ gat1_w,
        const float* __restrict__ fc1_w,
        uint4* __restrict__ Asw, uint4* __restrict__ Bsw,
        uint4* __restrict__ Ah, uint4* __restrict__ Al,
        uint4* __restrict__ Bh, uint4* __restrict__ Bl,
        float4* __restrict__ wgp, int* __restrict__ counts) {
    int blk = blockIdx.x;
    int t = threadIdx.x;
    int gflat = blk * 256 + t;
    if (gflat < BB * NN) counts[gflat] = 0;

    if (blk < 396) {                    // ---- prep A for xw1 (Kp=1056) ----
        int flat = gflat;
        int lane = flat & 63;
        int kc = (flat >> 6) % 33;
        int mt = flat / (33 * 64);
        int m = mt * 16 + (lane & 15);
        int k0 = kc * 32 + (lane >> 4) * 8;
        unsigned short vals[8];
        const float s = 1.0f / 800.0f;
#pragma unroll
        for (int j = 0; j < 8; j++) {
            int k = k0 + j;
            float v;
            if (k < CC) v = feats[(size_t)m * CC + k];
            else if (k < CC + 4) {
                const float* bx = boxes + (size_t)m * 4;
                int gk = k - CC;
                v = (gk == 0) ? bx[0] * s : (gk == 1) ? bx[1] * s
                  : (gk == 2) ? (bx[2] - bx[0]) * s : (bx[3] - bx[1]) * s;
            } else v = 0.f;
            vals[j] = f2bf(v);
        }
        uint4 pk;
        pk.x = (unsigned)vals[0] | ((unsigned)vals[1] << 16);
        pk.y = (unsigned)vals[2] | ((unsigned)vals[3] << 16);
        pk.z = (unsigned)vals[4] | ((unsigned)vals[5] << 16);
        pk.w = (unsigned)vals[6] | ((unsigned)vals[7] << 16);
        Asw[flat] = pk;
    } else if (blk < 924) {             // ---- prep B for xw1 (gat1_w, Kp=1056) ----
        int flat = gflat - 396 * 256;
        int lane = flat & 63;
        int kc = (flat >> 6) % 33;
        int nt = flat / (33 * 64);
        int n = nt * 16 + (lane & 15);
        int k0 = kc * 32 + (lane >> 4) * 8;
        unsigned short vals[8];
#pragma unroll
        for (int j = 0; j < 8; j++) {
            int k = k0 + j;
            float v = (k < CC + 4) ? gat1_w[(size_t)k * 1024 + n] : 0.f;
            vals[j] = f2bf(v);
        }
        uint4 pk;
        pk.x = (unsigned)vals[0] | ((unsigned)vals[1] << 16);
        pk.y = (unsigned)vals[2] | ((unsigned)vals[3] << 16);
        pk.z = (unsigned)vals[4] | ((unsigned)vals[5] << 16);
        pk.w = (unsigned)vals[6] | ((unsigned)vals[7] << 16);
        Bsw[flat] = pk;
    } else if (blk < 1308) {            // ---- prep A hi/lo for p12 (feats) ----
        int flat = gflat - 924 * 256;
        int lane = flat & 63;
        int kc = (flat >> 6) % 32;
        int mt = flat / (32 * 64);
        int m = mt * 16 + (lane & 15);
        int k0 = kc * 32 + (lane >> 4) * 8;
        unsigned short vh[8], vl[8];
        const float* src = feats + (size_t)m * CC + k0;
#pragma unroll
        for (int j = 0; j < 8; j++) {
            float v = src[j];
            unsigned short h = f2bf(v);
            vh[j] = h;
            vl[j] = f2bf(v - bf2f(h));
        }
        uint4 ph, pl;
        ph.x = (unsigned)vh[0] | ((unsigned)vh[1] << 16);
        ph.y = (unsigned)vh[2] | ((unsigned)vh[3] << 16);
        ph.z = (unsigned)vh[4] | ((unsigned)vh[5] << 16);
        ph.w = (unsigned)vh[6] | ((unsigned)vh[7] << 16);
        pl.x = (unsigned)vl[0] | ((unsigned)vl[1] << 16);
        pl.y = (unsigned)vl[2] | ((unsigned)vl[3] << 16);
        pl.z = (unsigned)vl[4] | ((unsigned)vl[5] << 16);
        pl.w = (unsigned)vl[6] | ((unsigned)vl[7] << 16);
        Ah[flat] = ph; Al[flat] = pl;
    } else if (blk < 1564) {            // ---- prep B hi/lo for p12 ([Wa|Wb]) ----
        int flat = gflat - 1308 * 256;
        int lane = flat & 63;
        int kc = (flat >> 6) % 32;
        int nt = flat / (32 * 64);
        int n = nt * 16 + (lane & 15);
        int k0 = kc * 32 + (lane >> 4) * 8;
        unsigned short vh[8], vl[8];
#pragma unroll
        for (int j = 0; j < 8; j++) {
            int k = k0 + j;
            float v = (n < 256) ? fc1_w[(size_t)k * 256 + n]
                                : fc1_w[(size_t)(CC + k) * 256 + (n - 256)];
            unsigned short h = f2bf(v);
            vh[j] = h;
            vl[j] = f2bf(v - bf2f(h));
        }
        uint4 ph, pl;
        ph.x = (unsigned)vh[0] | ((unsigned)vh[1] << 16);
        ph.y = (unsigned)vh[2] | ((unsigned)vh[3] << 16);
        ph.z = (unsigned)vh[4] | ((unsigned)vh[5] << 16);
        ph.w = (unsigned)vh[6] | ((unsigned)vh[7] << 16);
        pl.x = (unsigned)vl[0] | ((unsigned)vl[1] << 16);
        pl.y = (unsigned)vl[2] | ((unsigned)vl[3] << 16);
        pl.z = (unsigned)vl[4] | ((unsigned)vl[5] << 16);
        pl.w = (unsigned)vl[6] | ((unsigned)vl[7] << 16);
        Bh[flat] = ph; Bl[flat] = pl;
    } else {                            // ---- pack wg rows into float4 per c ----
        int c = t;
        float4 w;
        w.x = fc1_w[(size_t)(2 * CC + 0) * HR + c];
        w.y = fc1_w[(size_t)(2 * CC + 1) * HR + c];
        w.z = fc1_w[(size_t)(2 * CC + 2) * HR + c];
        w.w = fc1_w[(size_t)(2 * CC + 3) * HR + c];
        wgp[c] = w;
    }
}

// ---------------- xw1 via MFMA bf16 ----------------
__global__ __launch_bounds__(256) void k_xw1m(const uint4* __restrict__ Asw,
        const uint4* __restrict__ Bsw, float* __restrict__ xw1) {
    int t = threadIdx.x;
    int w = t >> 6;
    int lane = t & 63;
    int blk = blockIdx.x;            // mt*16 + ntgrp
    int mt = blk >> 4;
    int nt = (blk & 15) * 4 + w;
    f32x4 acc = {0.f, 0.f, 0.f, 0.f};
    const uint4* pa = Asw + (size_t)mt * 33 * 64 + lane;
    const uint4* pb = Bsw + (size_t)nt * 33 * 64 + lane;
#pragma unroll 4
    for (int kc = 0; kc < 33; kc++) {
        uint4 av = pa[kc * 64];
        uint4 bv = pb[kc * 64];
        acc = __builtin_amdgcn_mfma_f32_16x16x32_bf16(*(bf16x8*)&av, *(bf16x8*)&bv, acc, 0, 0, 0);
    }
    int col = nt * 16 + (lane & 15);
    int row0 = mt * 16 + (lane >> 4) * 4;
#pragma unroll
    for (int r = 0; r < 4; r++)
        xw1[(size_t)(row0 + r) * 1024 + col] = acc[r];
}

// ---------------- p1/p2 via split-bf16 MFMA (3 products) ----------------
__global__ __launch_bounds__(256) void k_p12m(const uint4* __restrict__ Ah,
        const uint4* __restrict__ Al, const uint4* __restrict__ Bh,
        const uint4* __restrict__ Bl, const float* __restrict__ fc1_b,
        float* __restrict__ p1, float* __restrict__ p2t) {
    int t = threadIdx.x;
    int w = t >> 6;
    int lane = t & 63;
    int blk = blockIdx.x;            // mt*8 + ntg
    int mt = blk >> 3;
    int nt = (blk & 7) * 4 + w;
    f32x4 acc = {0.f, 0.f, 0.f, 0.f};
    const uint4* pah = Ah + (size_t)mt * 32 * 64 + lane;
    const uint4* pal = Al + (size_t)mt * 32 * 64 + lane;
    const uint4* pbh = Bh + (size_t)nt * 32 * 64 + lane;
    const uint4* pbl = Bl + (size_t)nt * 32 * 64 + lane;
#pragma unroll 4
    for (int kc = 0; kc < 32; kc++) {
        uint4 ah = pah[kc * 64];
        uint4 al = pal[kc * 64];
        uint4 bh = pbh[kc * 64];
        uint4 bl = pbl[kc * 64];
        acc = __builtin_amdgcn_mfma_f32_16x16x32_bf16(*(bf16x8*)&ah, *(bf16x8*)&bh, acc, 0, 0, 0);
        acc = __builtin_amdgcn_mfma_f32_16x16x32_bf16(*(bf16x8*)&ah, *(bf16x8*)&bl, acc, 0, 0, 0);
        acc = __builtin_amdgcn_mfma_f32_16x16x32_bf16(*(bf16x8*)&al, *(bf16x8*)&bh, acc, 0, 0, 0);
    }
    int col = nt * 16 + (lane & 15);
    int row0 = mt * 16 + (lane >> 4) * 4;
    if (col < 256) {
        float bias = fc1_b[col];
#pragma unroll
        for (int r = 0; r < 4; r++)
            p1[(size_t)(row0 + r) * 256 + col] = acc[r] + bias;
    } else {
#pragma unroll
        for (int r = 0; r < 4; r++) {
            int rr = row0 + r;
            int b = rr / NN, rloc = rr % NN;
            p2t[((size_t)b * 256 + (col - 256)) * NN + rloc] = acc[r];
        }
    }
}

// ---------------- rel[i,j] : 1 row/block, scalar-pipe uniform operands ----------------
__global__ __launch_bounds__(384) void k_rel(const float* __restrict__ p1,
        const float* __restrict__ p2t, const float* __restrict__ boxes,
        const float4* __restrict__ wgp, const float* __restrict__ fc2_w,
        const float* __restrict__ fc2_b, float* __restrict__ rel) {
    int blk = blockIdx.x;            // b*NN + i
    int b = blk / NN;
    int i = blk - b * NN;
    int j = threadIdx.x;
    // uniform box of row i (scalar loads)
    float bi0 = boxes[(size_t)blk * 4 + 0];
    float bi1 = boxes[(size_t)blk * 4 + 1];
    float bi2 = boxes[(size_t)blk * 4 + 2];
    float bi3 = boxes[(size_t)blk * 4 + 3];
    float4 bj = *(const float4*)(boxes + ((size_t)b * NN + j) * 4);
    float g0 = fabsf(bi0 - bj.x);
    float g1 = fabsf(bi1 - bj.y);
    float g2 = fabsf(bi2 - bj.z);
    float g3 = fabsf(bi3 - bj.w);
    const float* p1row = p1 + (size_t)blk * HR;
    const float* p2b = p2t + (size_t)b * HR * NN + j;
    float acc = 0.f;
#pragma unroll 8
    for (int c = 0; c < HR; c++) {
        float4 w = wgp[c];           // wave-uniform -> s_load_dwordx4
        float p1c = p1row[c];        // wave-uniform -> s_load
        float wc = fc2_w[c];         // wave-uniform -> s_load
        float p2v = p2b[(size_t)c * NN];
        float v = p1c + p2v + g0 * w.x + g1 * w.y + g2 * w.z + g3 * w.w;
        v = fmaxf(v, 0.f);
        acc += v * wc;
    }
    float v = acc + fc2_b[0];
    if (j == i) v -= 1000000.0f;
    rel[(size_t)blk * NN + j] = v;
}

// ---------------- top-8 per row + edge scatter (merged) ----------------
__global__ __launch_bounds__(64) void k_topk_inv(const float* __restrict__ rel,
        int* __restrict__ counts, int* __restrict__ inlist) {
    int row = blockIdx.x;            // b*N+i
    int b = row / NN;
    int i = row - b * NN;
    int t = threadIdx.x;
    const float* r = rel + (size_t)row * NN;
    float v[6]; int id[6];
#pragma unroll
    for (int q = 0; q < 6; q++) { int j = t + q * 64; v[q] = r[j]; id[q] = j; }
    int mine = -1;
    for (int k = 0; k < TOPK; k++) {
        float bv = -INFINITY; int bi = NN;
#pragma unroll
        for (int q = 0; q < 6; q++) {
            if (v[q] > bv || (v[q] == bv && id[q] < bi)) { bv = v[q]; bi = id[q]; }
        }
        for (int off = 32; off > 0; off >>= 1) {
            float ov = __shfl_down(bv, off);
            int   oi = __shfl_down(bi, off);
            if (ov > bv || (ov == bv && oi < bi)) { bv = ov; bi = oi; }
        }
        bi = __shfl(bi, 0);
        if (t == k) mine = bi;
#pragma unroll
        for (int q = 0; q < 6; q++) if (id[q] == bi) v[q] = -INFINITY;
    }
    if (t < TOPK) {
        int tg = b * NN + mine;
        int q = atomicAdd(&counts[tg], 1);
        inlist[(size_t)tg * CAP + q] = i;
    } else if (t == TOPK) {          // self loop
        int q = atomicAdd(&counts[row], 1);
        inlist[(size_t)row * CAP + q] = i;
    }
}

// ---------------- attention dots for GAT1 (wave per head) ----------------
__global__ __launch_bounds__(256) void k_att1(const float* __restrict__ xw1,
        const float* __restrict__ att_src, const float* __restrict__ att_dst,
        float* __restrict__ a_s, float* __restrict__ a_d) {
    int node = blockIdx.x;
    int w = threadIdx.x >> 6;
    int lane = threadIdx.x & 63;
    const float4* xr = (const float4*)(xw1 + (size_t)node * 1024 + w * 256);
    const float4* sr = (const float4*)(att_src + w * 256);
    const float4* dr = (const float4*)(att_dst + w * 256);
    float4 x = xr[lane];
    float4 s = sr[lane];
    float4 d = dr[lane];
    float ps = x.x * s.x + x.y * s.y + x.z * s.z + x.w * s.w;
    float pd = x.x * d.x + x.y * d.y + x.z * d.z + x.w * d.w;
#pragma unroll
    for (int off = 32; off > 0; off >>= 1) {
        ps += __shfl_xor(ps, off);
        pd += __shfl_xor(pd, off);
    }
    if (lane == 0) {
        a_s[(size_t)node * NHEADS + w] = ps;
        a_d[(size_t)node * NHEADS + w] = pd;
    }
}

// ---------------- GAT1 aggregation: one block per (node, head) ----------------
__global__ __launch_bounds__(256) void k_agg1h(const int* __restrict__ counts,
        const int* __restrict__ inlist, const float* __restrict__ a_s,
        const float* __restrict__ a_d, const float* __restrict__ xw1,
        const float* __restrict__ gat1_b, float* __restrict__ h1) {
    __shared__ int slist[CAP];
    __shared__ float walpha[CAP];
    int blk = blockIdx.x;            // node*4 + h
    int node = blk >> 2;
    int h = blk & 3;
    int b = node / NN;
    int t = threadIdx.x;
    int deg = counts[node];
    for (int e = t; e < deg; e += 256) slist[e] = inlist[(size_t)node * CAP + e];
    __syncthreads();
    if (t < 64) {
        float ad = a_d[(size_t)node * NHEADS + h];
        float vals[7];
        int cnt = 0;
        float vmax = -INFINITY;
        for (int e = t; e < deg; e += 64) {
            float x = a_s[(size_t)(b * NN + slist[e]) * NHEADS + h] + ad;
            x = x >= 0.f ? x : NEG * x;
            vals[cnt++] = x;
            vmax = fmaxf(vmax, x);
        }
#pragma unroll
        for (int off = 32; off > 0; off >>= 1)
            vmax = fmaxf(vmax, __shfl_xor(vmax, off));
        float sum = 0.f;
        for (int i = 0; i < cnt; i++) {
            vals[i] = expf(vals[i] - vmax);
            sum += vals[i];
        }
#pragma unroll
        for (int off = 32; off > 0; off >>= 1)
            sum += __shfl_xor(sum, off);
        float inv = 1.f / fmaxf(sum, 1e-16f);
        cnt = 0;
        for (int e = t; e < deg; e += 64) walpha[e] = vals[cnt++] * inv;
    }
    __syncthreads();
    float acc = 0.f;
    for (int e = 0; e < deg; e++)
        acc += walpha[e] * xw1[(size_t)(b * NN + slist[e]) * 1024 + h * 256 + t];
    float o = acc + gat1_b[h * 256 + t];
    h1[(size_t)node * 1024 + h * 256 + t] = fmaxf(o, 0.f);
}

// ---------------- GAT2 projections + attention dots (one wave per node) ----------------
__global__ __launch_bounds__(64) void k_xw2att(const float* __restrict__ h1,
        const float* __restrict__ w2, const float* __restrict__ as2,
        const float* __restrict__ ad2, float* __restrict__ xw2,
        float* __restrict__ a_s2, float* __restrict__ a_d2) {
    int node = blockIdx.x;
    int lane = threadIdx.x;
    const float4* hr = (const float4*)(h1 + (size_t)node * 1024);
    float p0 = 0.f, p1v = 0.f;
#pragma unroll
    for (int q = 0; q < 4; q++) {
        float4 v = hr[lane + q * 64];
        int c = (lane + q * 64) * 4;
        float4 wa = *(const float4*)(w2 + c * 2);
        float4 wb = *(const float4*)(w2 + c * 2 + 4);
        p0  += v.x * wa.x + v.y * wa.z + v.z * wb.x + v.w * wb.z;
        p1v += v.x * wa.y + v.y * wa.w + v.z * wb.y + v.w * wb.w;
    }
#pragma unroll
    for (int off = 32; off > 0; off >>= 1) {
        p0 += __shfl_xor(p0, off);
        p1v += __shfl_xor(p1v, off);
    }
    if (lane == 0) {
        xw2[(size_t)node * 2] = p0;
        xw2[(size_t)node * 2 + 1] = p1v;
        a_s2[node] = p0 * as2[0] + p1v * as2[1];
        a_d2[node] = p0 * ad2[0] + p1v * ad2[1];
    }
}

// ---------------- GAT2 aggregation -> output (one wave per node) ----------------
__global__ __launch_bounds__(64) void k_agg2(const int* __restrict__ counts,
        const int* __restrict__ inlist, const float* __restrict__ a_s2,
        const float* __restrict__ a_d2, const float* __restrict__ xw2,
        const float* __restrict__ b2, float* __restrict__ out) {
    int node = blockIdx.x;
    int b = node / NN;
    int lane = threadIdx.x;
    int deg = counts[node];
    float ad = a_d2[node];
    float vals[7]; int srcs[7];
    int cnt = 0;
    float vmax = -INFINITY;
    for (int e = lane; e < deg; e += 64) {
        int s = b * NN + inlist[(size_t)node * CAP + e];
        float x = a_s2[s] + ad;
        x = x >= 0.f ? x : NEG * x;
        srcs[cnt] = s; vals[cnt] = x; cnt++;
        vmax = fmaxf(vmax, x);
    }
#pragma unroll
    for (int off = 32; off > 0; off >>= 1)
        vmax = fmaxf(vmax, __shfl_xor(vmax, off));
    float sum = 0.f;
    for (int i = 0; i < cnt; i++) {
        vals[i] = expf(vals[i] - vmax);
        sum += vals[i];
    }
#pragma unroll
    for (int off = 32; off > 0; off >>= 1)
        sum += __shfl_xor(sum, off);
    float inv = 1.f / fmaxf(sum, 1e-16f);
    float a0 = 0.f, a1 = 0.f;
    for (int i = 0; i < cnt; i++) {
        a0 += vals[i] * xw2[(size_t)srcs[i] * 2];
        a1 += vals[i] * xw2[(size_t)srcs[i] * 2 + 1];
    }
#pragma unroll
    for (int off = 32; off > 0; off >>= 1) {
        a0 += __shfl_xor(a0, off);
        a1 += __shfl_xor(a1, off);
    }
    if (lane == 0) {
        out[(size_t)node * 2]     = a0 * inv + b2[0];
        out[(size_t)node * 2 + 1] = a1 * inv + b2[1];
    }
}

extern "C" void kernel_launch(void* const* d_in, const int* in_sizes, int n_in,
                              void* d_out, int out_size, void* d_ws, size_t ws_size,
                              hipStream_t stream) {
    const float* feats  = (const float*)d_in[0];
    const float* boxes  = (const float*)d_in[1];
    const float* fc1_w  = (const float*)d_in[2];
    const float* fc1_b  = (const float*)d_in[3];
    const float* fc2_w  = (const float*)d_in[4];
    const float* fc2_b  = (const float*)d_in[5];
    const float* gat1_w = (const float*)d_in[6];
    const float* g1as   = (const float*)d_in[7];
    const float* g1ad   = (const float*)d_in[8];
    const float* gat1_b = (const float*)d_in[9];
    const float* gat2_w = (const float*)d_in[10];
    const float* g2as   = (const float*)d_in[11];
    const float* g2ad   = (const float*)d_in[12];
    const float* gat2_b = (const float*)d_in[13];
    float* out = (float*)d_out;

    char* ws = (char*)d_ws;
    size_t off = 0;
    auto alloc = [&](size_t bytes) -> void* {
        void* p = ws + off;
        off += (bytes + 255) / 256 * 256;
        return p;
    };
    int*   counts = (int*)alloc((size_t)BB * NN * 4);
    int*   inlist = (int*)alloc((size_t)BB * NN * CAP * 4);
    float* p1     = (float*)alloc((size_t)BB * NN * HR * 4);
    float* p2t    = (float*)alloc((size_t)BB * HR * NN * 4);
    float* rel    = (float*)alloc((size_t)BB * NN * NN * 4);
    float* xw1    = (float*)alloc((size_t)BB * NN * 1024 * 4);
    float* a_s1   = (float*)alloc((size_t)BB * NN * NHEADS * 4);
    float* a_d1   = (float*)alloc((size_t)BB * NN * NHEADS * 4);
    float* h1     = (float*)alloc((size_t)BB * NN * 1024 * 4);
    float* xw2    = (float*)alloc((size_t)BB * NN * 2 * 4);
    float* as2f   = (float*)alloc((size_t)BB * NN * 4);
    float* ad2f   = (float*)alloc((size_t)BB * NN * 4);
    uint4* Asw    = (uint4*)alloc((size_t)48 * 33 * 64 * 16);
    uint4* Bsw    = (uint4*)alloc((size_t)64 * 33 * 64 * 16);
    uint4* Ah     = (uint4*)alloc((size_t)48 * 32 * 64 * 16);
    uint4* Al     = (uint4*)alloc((size_t)48 * 32 * 64 * 16);
    uint4* Bh     = (uint4*)alloc((size_t)32 * 32 * 64 * 16);
    uint4* Bl     = (uint4*)alloc((size_t)32 * 32 * 64 * 16);
    float4* wgp   = (float4*)alloc((size_t)HR * 16);
    (void)ws_size; (void)in_sizes; (void)n_in; (void)out_size;

    k_prep<<<1565, 256, 0, stream>>>(feats, boxes, gat1_w, fc1_w,
                                     Asw, Bsw, Ah, Al, Bh, Bl, wgp, counts);
    k_p12m<<<48 * 8, 256, 0, stream>>>(Ah, Al, Bh, Bl, fc1_b, p1, p2t);
    k_rel<<<BB * NN, 384, 0, stream>>>(p1, p2t, boxes, wgp, fc2_w, fc2_b, rel);
    k_topk_inv<<<BB * NN, 64, 0, stream>>>(rel, counts, inlist);
    k_xw1m<<<48 * 16, 256, 0, stream>>>(Asw, Bsw, xw1);
    k_att1<<<BB * NN, 256, 0, stream>>>(xw1, g1as, g1ad, a_s1, a_d1);
    k_agg1h<<<BB * NN * NHEADS, 256, 0, stream>>>(counts, inlist, a_s1, a_d1, xw1, gat1_b, h1);
    k_xw2att<<<BB * NN, 64, 0, stream>>>(h1, gat2_w, g2as, g2ad, xw2, as2f, ad2f);
    k_agg2<<<BB * NN, 64, 0, stream>>>(counts, inlist, as2f, ad2f, xw2, gat2_b, out);
}